// Round 11
// baseline (2559.768 us; speedup 1.0000x reference)
//
#include <hip/hip_runtime.h>
#include <cstdint>
#include <cstddef>

// ---------------------------------------------------------------------------
// SNN "CatNet" forward, MFMA v6.
// Spiking tensors: uint8 [(n*64+t), C, H, W] (exact 0/1).
// All convs run as bf16 MFMA implicit-GEMM with hi/lo split weights.
// v6: conv K-loop uses LDS double-buffer + register prefetch (stage loads
// issued before MFMAs, written after; 1 barrier/chunk). 2x2 pools fused
// into IF / quantize kernels (no CF roundtrip for pool stages).
// ---------------------------------------------------------------------------

typedef short short8 __attribute__((ext_vector_type(8)));   // 8 bf16
typedef float floatx4 __attribute__((ext_vector_type(4)));

__device__ __forceinline__ unsigned short f2bf_rne(float f) {
  unsigned u = __float_as_uint(f);
  return (unsigned short)((u + 0x7FFFu + ((u >> 16) & 1u)) >> 16);
}
__device__ __forceinline__ float bf2f(unsigned short h) {
  return __uint_as_float((unsigned)h << 16);
}

// ---------------------------------------------------------------------------
// Weight pre-transform (3x3 layers): W f32 [Co][Ci][3][3] -> bf16 hi/lo frags.
// ---------------------------------------------------------------------------
__global__ __launch_bounds__(256) void k_wxform(const float* __restrict__ Wsrc,
                                                unsigned short* __restrict__ wt,
                                                int Ci, int Co) {
  const int nch = Ci >> 5;
  const int total = (Co >> 6) * nch * 9 * 4 * 64;
  int idx = blockIdx.x * 256 + threadIdx.x;
  if (idx >= total) return;
  int lane = idx & 63;
  int t2 = idx >> 6;
  int cg = t2 & 3;
  int t3 = t2 >> 2;
  int tap = t3 % 9;
  int t4 = t3 / 9;
  int ch = t4 % nch;
  int cot = t4 / nch;
  int co = cot * 64 + cg * 16 + (lane & 15);
  int cib = ch * 32 + (lane >> 4) * 8;
  short8 vh, vl;
  #pragma unroll
  for (int j = 0; j < 8; ++j) {
    float wv = Wsrc[((size_t)co * Ci + cib + j) * 9 + tap];
    unsigned short h = f2bf_rne(wv);
    vh[j] = (short)h;
    vl[j] = (short)f2bf_rne(wv - bf2f(h));
  }
  size_t base = ((((size_t)cot * nch + ch) * 9 + tap) * 4 + cg) * 1024 + (size_t)lane * 8;
  *(short8*)&wt[base] = vh;
  *(short8*)&wt[base + 512] = vl;
}

// L1 weight transform: W f32 [128][3][3][3] -> K=32 frags, k = tap*3+ci.
__global__ __launch_bounds__(256) void k_wxform1(const float* __restrict__ Wsrc,
                                                 unsigned short* __restrict__ wt) {
  int idx = blockIdx.x * 256 + threadIdx.x;   // 512 total
  if (idx >= 512) return;
  int lane = idx & 63, cg = (idx >> 6) & 3, cot = idx >> 8;
  int co = cot * 64 + cg * 16 + (lane & 15);
  short8 vh, vl;
  #pragma unroll
  for (int e = 0; e < 8; ++e) {
    int k = (lane >> 4) * 8 + e;
    float wv = 0.f;
    if (k < 27) { int tap = k / 3, ci = k - 3 * tap; wv = Wsrc[(co * 3 + ci) * 9 + tap]; }
    unsigned short h = f2bf_rne(wv);
    vh[e] = (short)h;
    vl[e] = (short)f2bf_rne(wv - bf2f(h));
  }
  size_t base = (size_t)cot * 4096 + cg * 1024 + (size_t)lane * 8;
  *(short8*)&wt[base] = vh;
  *(short8*)&wt[base + 512] = vl;
}

// Transpose+pack x: [n][c][hw][t] f32 -> XT2[(n*64+t)][c][hw] u32 = hi|lo<<16
__global__ __launch_bounds__(256) void k_tpack(const float* __restrict__ x,
                                               unsigned* __restrict__ XT2) {
  int idx = blockIdx.x * 256 + threadIdx.x;   // 786432
  int b = idx / 3072;
  int rem = idx - b * 3072;
  int t = b & 63, n = b >> 6;
  float f = x[((size_t)(n * 3072 + rem)) * 64 + t];
  unsigned short h = f2bf_rne(f);
  unsigned short l = f2bf_rne(f - bf2f(h));
  XT2[idx] = (unsigned)h | ((unsigned)l << 16);
}

__global__ __launch_bounds__(256) void k_xbar_pack(const float* __restrict__ x,
                                                   unsigned* __restrict__ xb) {
  int idx = blockIdx.x * 256 + threadIdx.x;   // 12288
  if (idx >= 12288) return;
  const float* p = x + (size_t)idx * 64;
  float s = 0.f;
  #pragma unroll
  for (int t = 0; t < 64; ++t) s += p[t];
  s *= 0.015625f;
  unsigned short h = f2bf_rne(s);
  unsigned short l = f2bf_rne(s - bf2f(h));
  xb[idx] = (unsigned)h | ((unsigned)l << 16);
}

// ---------------------------------------------------------------------------
// MFMA conv, generic 3x3. PAD0=false: pad=1 square W; PAD0=true: L7 (4x4->2x2).
// Block: 256 thr / 4 waves; wave-tile 64co x (G*16)px. A from global (per-tap
// double buffer), B from LDS (stride-40-short rows, conflict-free b128).
// Non-PAD0: LDS double-buffered input staging with register prefetch.
// grid.z = K-split: chunks [z*nchPer, (z+1)*nchPer), out += z*osplit.
// ---------------------------------------------------------------------------
template <typename T, bool PAD0, int G>
__global__ __launch_bounds__(256, 1) void k_cmfma(
    const T* __restrict__ in, const unsigned short* __restrict__ wt,
    const float* __restrict__ bs, float* __restrict__ out,
    int Ci, int Co, int W, int TRI, int tpi, int NIMG, int nImgValid,
    int nchPer, size_t osplit) {
  constexpr int MT = 4 * G * 16;             // block m-tile
  constexpr int PPXMAX = PAD0 ? (MT / 4) * 16 : 208;
  constexpr int NBUF = PAD0 ? 1 : 2;
  __shared__ unsigned short sIn[NBUF][PPXMAX * 40];
  const int tid = threadIdx.x;
  const int lane = tid & 63;
  const int wv = tid >> 6;
  const int cot = blockIdx.x;
  const int mtile = blockIdx.y;
  const int kz = blockIdx.z;
  const int nch = Ci >> 5;
  const int nchA = kz * nchPer, nchB = nchA + nchPer;
  out += (size_t)kz * osplit;
  const int addBias = (kz == 0);

  int img_first, r0 = 0, PPR, PPX;
  if constexpr (PAD0) {
    img_first = mtile * (MT / 4);
    PPR = 16; PPX = (MT / 4) * 16;
  } else {
    img_first = (mtile / tpi) * NIMG;
    r0 = (mtile % tpi) * TRI;
    PPR = (TRI + 2) * (W + 2);
    PPX = NIMG * PPR;
  }
  const int TRW = TRI * W;

  // output / B-fragment mapping
  int p0[G], mimg[G], mopx[G];
  #pragma unroll
  for (int g = 0; g < G; ++g) {
    int m = wv * (G * 16) + g * 16 + (lane & 15);
    int limg;
    if constexpr (PAD0) {
      limg = m >> 2;
      int o = m & 3;
      p0[g] = limg * 16 + (o >> 1) * 4 + (o & 1);
      mopx[g] = (o >> 1) * 2 + (o & 1);
    } else {
      limg = m / TRW;
      int rm = m - limg * TRW;
      int r = rm / W, c = rm - r * W;
      p0[g] = limg * PPR + r * (W + 2) + c;
      mopx[g] = (r0 + r) * W + c;
    }
    mimg[g] = img_first + limg;
  }
  int psh[9];
  #pragma unroll
  for (int t = 0; t < 9; ++t) {
    int dh = t / 3, dw = t - dh * 3;
    psh[t] = PAD0 ? (dh * 4 + dw) : (dh * (W + 2) + dw);
  }

  // staging precompute (<=2 px per thread), idiv only here
  const int HWin = PAD0 ? 16 : W * W;
  int sgofs[2]; bool svalid[2];
  #pragma unroll
  for (int i = 0; i < 2; ++i) {
    int p = tid + i * 256;
    svalid[i] = false; sgofs[i] = 0;
    if (p < PPX) {
      int limg, gpx;
      if constexpr (PAD0) {
        limg = p >> 4; gpx = p & 15;
      } else {
        limg = p / PPR;
        int rem = p - limg * PPR;
        int pr = rem / (W + 2), pc = rem - pr * (W + 2);
        int gr = r0 + pr - 1, gc = pc - 1;
        gpx = (gr >= 0 && gr < W && gc >= 0 && gc < W) ? gr * W + gc : -1;
      }
      int img = img_first + limg;
      if (gpx >= 0 && img < nImgValid) {
        svalid[i] = true;
        sgofs[i] = img * Ci * HWin + gpx;
      }
    }
  }
  const int kb = (lane >> 4) * 8;

  auto stage_direct = [&](int ch, unsigned short* buf) {
    const int ci0 = ch * 32;
    #pragma unroll
    for (int i = 0; i < 2; ++i) {
      int p = tid + i * 256;
      if (p < PPX) {
        unsigned short* dst = &buf[p * 40];
        if (svalid[i]) {
          const T* sp = in + sgofs[i] + (size_t)ci0 * HWin;
          #pragma unroll
          for (int j = 0; j < 4; ++j) {
            short8 v;
            #pragma unroll
            for (int e = 0; e < 8; ++e) {
              if constexpr (sizeof(T) == 1)
                v[e] = sp[(size_t)(j * 8 + e) * HWin] ? (short)0x3F80 : (short)0;
              else
                v[e] = (short)f2bf_rne(((const float*)sp)[(size_t)(j * 8 + e) * HWin]);
            }
            *(short8*)&dst[j * 8] = v;
          }
        } else {
          short8 z = {};
          #pragma unroll
          for (int j = 0; j < 4; ++j) *(short8*)&dst[j * 8] = z;
        }
      }
    }
  };

  floatx4 acc[4][G];
  floatx4 zero = {0.f, 0.f, 0.f, 0.f};
  #pragma unroll
  for (int cg = 0; cg < 4; ++cg)
    #pragma unroll
    for (int g = 0; g < G; ++g) acc[cg][g] = zero;

  stage_direct(nchA, sIn[0]);
  __syncthreads();

  for (int ch = nchA; ch < nchB; ++ch) {
    const int cur = (NBUF == 2) ? ((ch - nchA) & 1) : 0;
    const bool pre = (ch + 1 < nchB);
    // ---- issue next-chunk staging loads into regs (retire under MFMA) ----
    uint8_t ru[2][32];
    float rf[2][32];
    if (NBUF == 2 && pre) {
      const int ci0n = (ch + 1) * 32;
      #pragma unroll
      for (int i = 0; i < 2; ++i) {
        if (tid + i * 256 < PPX && svalid[i]) {
          const T* sp = in + sgofs[i] + (size_t)ci0n * HWin;
          #pragma unroll
          for (int k = 0; k < 32; ++k) {
            if constexpr (sizeof(T) == 1) ru[i][k] = sp[(size_t)k * HWin];
            else rf[i][k] = ((const float*)sp)[(size_t)k * HWin];
          }
        }
      }
    }
    // ---- taps: A from global (double-buffered), B from LDS ----
    const unsigned short* wb = wt + ((size_t)(cot * nch + ch)) * 36864 + (size_t)lane * 8;
    short8 A[2][8];
    #pragma unroll
    for (int f = 0; f < 8; ++f)
      A[0][f] = *(const short8*)(wb + (f >> 1) * 1024 + (f & 1) * 512);
    #pragma unroll
    for (int t = 0; t < 9; ++t) {
      const int curA = t & 1;
      if (t < 8) {
        #pragma unroll
        for (int f = 0; f < 8; ++f)
          A[curA ^ 1][f] = *(const short8*)(wb + (size_t)(t + 1) * 4096 + (f >> 1) * 1024 + (f & 1) * 512);
      }
      short8 b[G];
      #pragma unroll
      for (int g = 0; g < G; ++g)
        b[g] = *(const short8*)&sIn[cur][(p0[g] + psh[t]) * 40 + kb];
      #pragma unroll
      for (int cg = 0; cg < 4; ++cg) {
        #pragma unroll
        for (int g = 0; g < G; ++g) {
          acc[cg][g] = __builtin_amdgcn_mfma_f32_16x16x32_bf16(A[curA][cg * 2 + 0], b[g], acc[cg][g], 0, 0, 0);
          acc[cg][g] = __builtin_amdgcn_mfma_f32_16x16x32_bf16(A[curA][cg * 2 + 1], b[g], acc[cg][g], 0, 0, 0);
        }
      }
    }
    // ---- write prefetched chunk to the other LDS buffer ----
    if (NBUF == 2) {
      if (pre) {
        #pragma unroll
        for (int i = 0; i < 2; ++i) {
          int p = tid + i * 256;
          if (p < PPX) {
            unsigned short* dst = &sIn[cur ^ 1][p * 40];
            if (svalid[i]) {
              #pragma unroll
              for (int j = 0; j < 4; ++j) {
                short8 v;
                #pragma unroll
                for (int e = 0; e < 8; ++e) {
                  if constexpr (sizeof(T) == 1)
                    v[e] = ru[i][j * 8 + e] ? (short)0x3F80 : (short)0;
                  else
                    v[e] = (short)f2bf_rne(rf[i][j * 8 + e]);
                }
                *(short8*)&dst[j * 8] = v;
              }
            } else {
              short8 z = {};
              #pragma unroll
              for (int j = 0; j < 4; ++j) *(short8*)&dst[j * 8] = z;
            }
          }
        }
      }
      __syncthreads();
    } else {
      __syncthreads();
      if (pre) stage_direct(ch + 1, sIn[0]);
      __syncthreads();
    }
  }
  // ---- epilogue: row=(lane>>4)*4+i -> co, col=lane&15 -> px ----
  const int HWout = PAD0 ? 4 : W * W;
  #pragma unroll
  for (int g = 0; g < G; ++g) {
    if (mimg[g] >= nImgValid) continue;
    #pragma unroll
    for (int cg = 0; cg < 4; ++cg) {
      #pragma unroll
      for (int i2 = 0; i2 < 4; ++i2) {
        int co = cot * 64 + cg * 16 + (lane >> 4) * 4 + i2;
        float bv = addBias ? bs[co] : 0.f;
        out[((size_t)mimg[g] * Co + co) * HWout + mopx[g]] = acc[cg][g][i2] + bv;
      }
    }
  }
}

// ---------------------------------------------------------------------------
// L1 MFMA conv: K=32 im2col (k=tap*3+ci), input packed hi/lo u32.
// ---------------------------------------------------------------------------
__global__ __launch_bounds__(256, 1) void k_l1(const unsigned* __restrict__ xin,
                                               const unsigned short* __restrict__ wt,
                                               const float* __restrict__ bs,
                                               float* __restrict__ out,
                                               int nImgValid) {
  __shared__ unsigned short sIn[256 * 72];   // [m][hi(32) | lo(32)], stride 72
  const int tid = threadIdx.x, lane = tid & 63, wv = tid >> 6;
  const int cot = blockIdx.x, mtile = blockIdx.y;
  const int img = mtile >> 2;
  const int r0 = (mtile & 3) * 8;
  {
    int m = tid;
    int r = r0 + (m >> 5), c = m & 31;
    const unsigned* ip = xin + (size_t)img * 3072;
    unsigned v[9][3];
    bool iv = (img < nImgValid);
    #pragma unroll
    for (int dh = 0; dh < 3; ++dh) {
      #pragma unroll
      for (int dw = 0; dw < 3; ++dw) {
        int rr = r + dh - 1, cc = c + dw - 1;
        bool ok = iv && rr >= 0 && rr < 32 && cc >= 0 && cc < 32;
        #pragma unroll
        for (int ci = 0; ci < 3; ++ci)
          v[dh * 3 + dw][ci] = ok ? ip[ci * 1024 + rr * 32 + cc] : 0u;
      }
    }
    #pragma unroll
    for (int j = 0; j < 4; ++j) {
      short8 vh, vl;
      #pragma unroll
      for (int e = 0; e < 8; ++e) {
        int k = j * 8 + e;
        unsigned u = (k < 27) ? v[k / 3][k - 3 * (k / 3)] : 0u;
        vh[e] = (short)(u & 0xFFFFu);
        vl[e] = (short)(u >> 16);
      }
      *(short8*)&sIn[m * 72 + j * 8] = vh;
      *(short8*)&sIn[m * 72 + 32 + j * 8] = vl;
    }
  }
  __syncthreads();
  const int kb = (lane >> 4) * 8;
  const unsigned short* wb = wt + (size_t)cot * 4096 + (size_t)lane * 8;
  short8 Af[8];
  #pragma unroll
  for (int f = 0; f < 8; ++f)
    Af[f] = *(const short8*)(wb + (f >> 1) * 1024 + (f & 1) * 512);
  floatx4 acc[4][4];
  floatx4 zero = {0.f, 0.f, 0.f, 0.f};
  #pragma unroll
  for (int cg = 0; cg < 4; ++cg)
    #pragma unroll
    for (int g = 0; g < 4; ++g) acc[cg][g] = zero;
  short8 bh[4], bl[4];
  #pragma unroll
  for (int g = 0; g < 4; ++g) {
    int m = wv * 64 + g * 16 + (lane & 15);
    bh[g] = *(const short8*)&sIn[m * 72 + kb];
    bl[g] = *(const short8*)&sIn[m * 72 + 32 + kb];
  }
  #pragma unroll
  for (int cg = 0; cg < 4; ++cg) {
    #pragma unroll
    for (int g = 0; g < 4; ++g) {
      acc[cg][g] = __builtin_amdgcn_mfma_f32_16x16x32_bf16(Af[cg * 2 + 0], bh[g], acc[cg][g], 0, 0, 0);
      acc[cg][g] = __builtin_amdgcn_mfma_f32_16x16x32_bf16(Af[cg * 2 + 0], bl[g], acc[cg][g], 0, 0, 0);
      acc[cg][g] = __builtin_amdgcn_mfma_f32_16x16x32_bf16(Af[cg * 2 + 1], bh[g], acc[cg][g], 0, 0, 0);
    }
  }
  if (img >= nImgValid) return;
  #pragma unroll
  for (int g = 0; g < 4; ++g) {
    int mbase = wv * 64 + g * 16 + (lane & 15);
    int px = (r0 + (mbase >> 5)) * 32 + (mbase & 31);
    #pragma unroll
    for (int cg = 0; cg < 4; ++cg) {
      #pragma unroll
      for (int i2 = 0; i2 < 4; ++i2) {
        int co = cot * 64 + cg * 16 + (lane >> 4) * 4 + i2;
        out[((size_t)img * 128 + co) * 1024 + px] = acc[cg][g][i2] + bs[co];
      }
    }
  }
}

// ---------------------------------------------------------------------------
// Integrate-and-fire; blockIdx.y = 64-t group. Sums nparts partials.
__global__ __launch_bounds__(256) void k_if(const float* __restrict__ X,
                                            uint8_t* __restrict__ Sp,
                                            const float* __restrict__ th,
                                            float* __restrict__ ssum,
                                            int C, int HW,
                                            int nparts, size_t pstride) {
  const int CHW = C * HW;
  int idx = blockIdx.x * 256 + threadIdx.x;
  if (idx >= CHW) return;
  int c = idx / HW;
  const float thv = th[c];
  size_t base = (size_t)blockIdx.y * 64 * CHW + idx;
  const float* p = X + base;
  uint8_t* q = Sp + base;
  float v = 0.f, ss = 0.f;
  #pragma unroll
  for (int t = 0; t < 64; ++t) {
    const float* pt = p + (size_t)t * CHW;
    float xv = pt[0];
    for (int u = 1; u < nparts; ++u) xv += pt[(size_t)u * pstride];
    v += xv;
    float s = (v >= thv) ? 1.f : 0.f;
    v -= s * thv;
    q[(size_t)t * CHW] = (uint8_t)s;
    ss += s;
  }
  if ((HW & 63) == 0) {
    for (int off = 32; off >= 1; off >>= 1) ss += __shfl_down(ss, off);
    if ((threadIdx.x & 63) == 0) atomicAdd(&ssum[c], ss);
  } else {
    atomicAdd(&ssum[c], ss);
  }
}

// Fused 2x2 avg-pool + integrate-and-fire on uint8 spikes.
// Sin [(n*64+t), C, H, H] u8 -> Sp [(n*64+t), C, HWo] u8; Sout (HWo==1 only).
__global__ __launch_bounds__(256) void k_ifpool(const uint8_t* __restrict__ Sin,
                                                uint8_t* __restrict__ Sp,
                                                const float* __restrict__ th,
                                                float* __restrict__ ssum,
                                                float* __restrict__ Sout,
                                                int C, int H) {
  const int Ho = H >> 1, HWo = Ho * Ho;
  const int CHWo = C * HWo;
  int idx = blockIdx.x * 256 + threadIdx.x;
  if (idx >= CHWo) return;
  int c = idx / HWo;
  int rem = idx - c * HWo;
  int ho = rem / Ho, wo = rem - ho * Ho;
  const float thv = th[c];
  const size_t istep = (size_t)C * H * H;
  const size_t ib = ((size_t)(blockIdx.y * 64) * C + c) * (H * H) + (2 * ho) * H + 2 * wo;
  uint8_t* q = Sp + (size_t)blockIdx.y * 64 * CHWo + idx;
  float v = 0.f, ss = 0.f;
  #pragma unroll
  for (int t = 0; t < 64; ++t) {
    const uint8_t* pp = Sin + ib + (size_t)t * istep;
    float xv = 0.25f * ((float)pp[0] + (float)pp[1] + (float)pp[H] + (float)pp[H + 1]);
    v += xv;
    float s = (v >= thv) ? 1.f : 0.f;
    v -= s * thv;
    q[(size_t)t * CHWo] = (uint8_t)s;
    ss += s;
  }
  if (Sout && HWo == 1) Sout[blockIdx.y * C + c] = ss;
  if ((HWo & 63) == 0) {
    for (int off = 32; off >= 1; off >>= 1) ss += __shfl_down(ss, off);
    if ((threadIdx.x & 63) == 0) atomicAdd(&ssum[c], ss);
  } else {
    atomicAdd(&ssum[c], ss);
  }
}

// Fused 2x2 avg-pool + quantize on analog path (batch 4).
__global__ __launch_bounds__(256) void k_ttypool(const float* __restrict__ yin,
                                                 float* __restrict__ yout,
                                                 float* __restrict__ ysum,
                                                 int C, int H) {
  const int Ho = H >> 1, HWo = Ho * Ho;
  int idx = blockIdx.x * 256 + threadIdx.x;
  if (idx >= 4 * C * HWo) return;
  int rem = idx % (C * HWo);
  int c = rem / HWo;
  int r2 = rem - c * HWo;
  int ho = r2 / Ho, wo = r2 - ho * Ho;
  int img = idx / (C * HWo);
  size_t base = (((size_t)img * C + c) * H + 2 * ho) * H + 2 * wo;
  float xv = 0.25f * (yin[base] + yin[base + 1] + yin[base + H] + yin[base + H + 1]);
  float v = floorf(xv * 64.f) * 0.015625f;
  v = fminf(fmaxf(v, 0.f), 1.f);
  yout[idx] = v;
  if ((HWo & 63) == 0) {
    for (int off = 32; off >= 1; off >>= 1) v += __shfl_down(v, off);
    if ((threadIdx.x & 63) == 0) atomicAdd(&ysum[c], v);
  } else {
    atomicAdd(&ysum[c], v);
  }
}

// Analog quantize; sums nparts partial conv outputs (K-split) first.
__global__ __launch_bounds__(256) void k_tty(const float* __restrict__ y4,
                                             float* __restrict__ yout,
                                             float* __restrict__ ysum,
                                             int C, int HW,
                                             int nparts, int pstride) {
  int idx = blockIdx.x * 256 + threadIdx.x;
  if (idx >= 4 * C * HW) return;
  int rem = idx % (C * HW);
  int c = rem / HW;
  float xv = 0.f;
  for (int p = 0; p < nparts; ++p) xv += y4[idx + (size_t)p * pstride];
  float v = floorf(xv * 64.f) * 0.015625f;
  v = fminf(fmaxf(v, 0.f), 1.f);
  yout[idx] = v;
  if ((HW & 63) == 0) {
    for (int off = 32; off >= 1; off >>= 1) v += __shfl_down(v, off);
    if ((threadIdx.x & 63) == 0) atomicAdd(&ysum[c], v);
  } else {
    atomicAdd(&ysum[c], v);
  }
}

__global__ void k_thr(const float* __restrict__ thin,
                      const float* __restrict__ ssum,
                      const float* __restrict__ ysum,
                      float* __restrict__ dst, int C, float invmul) {
  int c = blockIdx.x * 256 + threadIdx.x;
  if (c >= C) return;
  float diff = (ysum[c] * 64.f - ssum[c]) * invmul;
  dst[c] = thin[c] - 0.1f * diff;
}

__global__ void k_cls(const float* __restrict__ S, const float* __restrict__ wc,
                      const float* __restrict__ bcp, float* __restrict__ out) {
  int idx = blockIdx.x * 256 + threadIdx.x;
  if (idx >= 400) return;
  int n = idx / 100, o = idx - (idx / 100) * 100;
  const float* sp = S + n * 1024;
  const float* wp = wc + o * 1024;
  float acc = 0.f;
  for (int c = 0; c < 1024; ++c) acc += wp[c] * sp[c];
  out[idx] = acc * 0.015625f + bcp[o];
}

extern "C" void kernel_launch(void* const* d_in, const int* in_sizes, int n_in,
                              void* d_out_v, int out_size, void* d_ws, size_t ws_size,
                              hipStream_t stream) {
  const float *Ws[7], *Bs[7], *Wa[7], *Ba[7];
  for (int i = 0; i < 7; ++i) {
    Ws[i] = (const float*)d_in[i * 4 + 0];
    Bs[i] = (const float*)d_in[i * 4 + 1];
    Wa[i] = (const float*)d_in[i * 4 + 2];
    Ba[i] = (const float*)d_in[i * 4 + 3];
  }
  const float* wc = (const float*)d_in[28];
  const float* bc = (const float*)d_in[29];
  const float* x  = (const float*)d_in[30];
  const float* TH[7];
  for (int i = 0; i < 7; ++i) TH[i] = (const float*)d_in[31 + i];
  const float* P[4];
  for (int i = 0; i < 4; ++i) P[i] = (const float*)d_in[38 + i];
  float* out = (float*)d_out_v;

  // ---- workspace (107.7 MB) ----
  float* w = (float*)d_ws;
  const size_t RF = 8536064;      // [WT | CF0] region, per-layer split
  float* Rb = w;
  size_t off = RF;
  float* xbar = w + off; off += 12288;    // packed u32 hi/lo
  float* yA   = w + off; off += 524288;
  float* yB   = w + off; off += 524288;
  float* y4   = w + off; off += 524288;
  float* S    = w + off; off += 4096;
  float* sums = w + off; off += 11 * 2048;
  uint8_t* SA = (uint8_t*)(w + off);
  uint8_t* SB = SA + 33554432;
  size_t total_bytes = off * sizeof(float) + (size_t)2 * 33554432;
  if (ws_size < total_bytes) return;
  unsigned short* WT = (unsigned short*)Rb;
  unsigned* XT2 = (unsigned*)SB;          // aliases SB (dead until L2 output)
  unsigned* xbar2 = (unsigned*)xbar;

  hipMemsetAsync(sums, 0, 11 * 2048 * sizeof(float), stream);
  k_tpack<<<3072, 256, 0, stream>>>(x, XT2);
  k_xbar_pack<<<48, 256, 0, stream>>>(x, xbar2);

  int stage = 0;

  // ---- L1 (MFMA im2col) ----
  {
    float* CF = Rb + 4096;                 // WT1 = 16 KB
    float* ss = sums; float* ys = ss + 1024;
    k_wxform1<<<2, 256, 0, stream>>>(Ws[0], WT);
    for (int c = 0; c < 4; ++c) {
      k_l1<<<dim3(2, 256), 256, 0, stream>>>(XT2 + (size_t)c * 64 * 3072, WT, Bs[0], CF, 64);
      k_if<<<dim3(512, 1), 256, 0, stream>>>(CF, SA + (size_t)c * 64 * 131072,
                                             TH[0], ss, 128, 1024, 1, 0);
    }
    k_wxform1<<<2, 256, 0, stream>>>(Wa[0], WT);
    k_l1<<<dim3(2, 16), 256, 0, stream>>>(xbar2, WT, Ba[0], y4, 4);
    k_tty<<<2048, 256, 0, stream>>>(y4, yA, ys, 128, 1024, 1, 0);
    k_thr<<<1, 256, 0, stream>>>(TH[0], ss, ys, out + 400, 128, 1.0f / (4.f * 1024.f * 64.f));
    ++stage;
  }

  // ---- generic pad=1 MFMA layer ----
  auto mfma_layer = [&](const uint8_t* inS, uint8_t* outS, const float* inY, float* outY,
                        int li, int Ci, int Co, int W, int TRI, int tpi, int NIMG,
                        int chunkImgs, int kzn, float* CF1,
                        int aTRI, int atpi, int akz,
                        const float* thin, int outoff) {
    const int HW = W * W;
    const int CHWo = Co * HW;
    const int nch = Ci >> 5;
    float* ss = sums + stage * 2048; float* ys = ss + 1024;
    float* CF = Rb + (size_t)Co * Ci * 9;
    size_t osplit = (kzn == 2) ? (size_t)(CF1 - CF) : 0;
    int xgrid = ((Co / 64) * nch * 9 * 4 * 64 + 255) / 256;
    k_wxform<<<xgrid, 256, 0, stream>>>(Ws[li], WT, Ci, Co);
    int nchk = 256 / chunkImgs;
    int mt = (chunkImgs / NIMG) * tpi;
    for (int c = 0; c < nchk; ++c) {
      k_cmfma<uint8_t, false, 2><<<dim3(Co / 64, mt, kzn), 256, 0, stream>>>(
          inS + (size_t)c * chunkImgs * Ci * HW, WT, Bs[li], CF,
          Ci, Co, W, TRI, tpi, NIMG, chunkImgs, nch / kzn, osplit);
      k_if<<<dim3((CHWo + 255) / 256, chunkImgs / 64), 256, 0, stream>>>(
          CF, outS + (size_t)c * chunkImgs * CHWo, thin, ss, Co, HW, kzn, osplit);
    }
    k_wxform<<<xgrid, 256, 0, stream>>>(Wa[li], WT, Ci, Co);
    int aosplit = 4 * CHWo;
    k_cmfma<float, false, 1><<<dim3(Co / 64, 4 * atpi, akz), 256, 0, stream>>>(
        inY, WT, Ba[li], y4, Ci, Co, W, aTRI, atpi, 1, 4, nch / akz, (size_t)aosplit);
    k_tty<<<(4 * CHWo + 255) / 256, 256, 0, stream>>>(y4, outY, ys, Co, HW, akz, aosplit);
    k_thr<<<(Co + 255) / 256, 256, 0, stream>>>(thin, ss, ys, out + outoff, Co,
                                                1.0f / (4.f * HW * 64.f));
    ++stage;
  };

  auto pool_stage = [&](const uint8_t* inS, uint8_t* outS, const float* inY, float* outY,
                        int C, int H, const float* pthr, int outoff, float* Sout) {
    const int Ho = H / 2, HWo = Ho * Ho;
    const int CHWo = C * HWo;
    float* ss = sums + stage * 2048; float* ys = ss + 1024;
    k_ifpool<<<dim3((CHWo + 255) / 256, 4), 256, 0, stream>>>(inS, outS, pthr, ss, Sout, C, H);
    k_ttypool<<<(4 * CHWo + 255) / 256, 256, 0, stream>>>(inY, outY, ys, C, H);
    k_thr<<<(C + 255) / 256, 256, 0, stream>>>(pthr, ss, ys, out + outoff, C,
                                               1.0f / (4.f * HWo * 64.f));
    ++stage;
  };

  // L2: spike G=2 TRI=4,tpi=8 -> grid(2,512,1)=1024; analog aTRI=2,atpi=16
  mfma_layer(SA, SB, yA, yB, 1, 128, 128, 32, 4, 8, 1, 64, 1, nullptr,
             2, 16, 1, TH[1], 528);
  // P1
  pool_stage(SB, SA, yB, yA, 128, 32, P[0], 3216, nullptr);
  // L3: spike TRI=8,tpi=2, kz=2 (partial SB tail) -> grid(4,128,2)=1024
  mfma_layer(SA, SB, yA, yB, 2, 128, 256, 16, 8, 2, 1, 64, 2,
             (float*)(SB + 16777216), 4, 4, 2, TH[2], 656);
  // L4
  mfma_layer(SB, SA, yB, yA, 3, 256, 256, 16, 8, 2, 1, 64, 2,
             (float*)(SA + 16777216), 4, 4, 2, TH[3], 912);
  // P2
  pool_stage(SA, SB, yA, yB, 256, 16, P[1], 3344, nullptr);
  // L5: spike NIMG=2,TRI=8,tpi=1, kz=2 -> grid(8,64,2)=1024
  mfma_layer(SB, SA, yB, yA, 4, 256, 512, 8, 8, 1, 2, 128, 2,
             (float*)(SA + 8388608), 8, 1, 4, TH[4], 1168);
  // L6
  mfma_layer(SA, SB, yA, yB, 5, 512, 512, 8, 8, 1, 2, 128, 2,
             (float*)(SB + 8388608), 8, 1, 4, TH[5], 1680);
  // P3
  pool_stage(SB, SA, yB, yA, 512, 8, P[2], 3600, nullptr);
  // L7 (pad=0): spike kz=4, partials in SA tail; analog G=1 akz=8 in y4
  {
    float* ss = sums + stage * 2048; float* ys = ss + 1024;
    float* CF = (float*)(SA + 4194304);         // 4 partials x 4.2 MB
    const size_t osplit = 1048576;              // 256*1024*4 elems
    int xgrid = (16 * 16 * 9 * 4 * 64 + 255) / 256;
    k_wxform<<<xgrid, 256, 0, stream>>>(Ws[6], WT, 512, 1024);
    k_cmfma<uint8_t, true, 2><<<dim3(16, 8, 4), 256, 0, stream>>>(
        SA, WT, Bs[6], CF, 512, 1024, 4, 0, 1, 0, 256, 4, osplit);
    k_if<<<dim3(16, 4), 256, 0, stream>>>(CF, SB, TH[6], ss, 1024, 4, 4, osplit);
    k_wxform<<<xgrid, 256, 0, stream>>>(Wa[6], WT, 512, 1024);
    k_cmfma<float, true, 1><<<dim3(16, 1, 8), 256, 0, stream>>>(
        yA, WT, Ba[6], y4, 512, 1024, 4, 0, 1, 0, 4, 2, 16384);
    k_tty<<<64, 256, 0, stream>>>(y4, yB, ys, 1024, 4, 8, 16384);
    k_thr<<<4, 256, 0, stream>>>(TH[6], ss, ys, out + 2192, 1024, 1.0f / 1024.f);
    ++stage;
  }
  // P4: fused pool+IF also writes S directly
  pool_stage(SB, SA, yB, yA, 1024, 2, P[3], 4112, S);
  // classifier
  k_cls<<<2, 256, 0, stream>>>(S, wc, bc, out);
}

// Round 12
// 2031.279 us; speedup vs baseline: 1.2602x; 1.2602x over previous
//
#include <hip/hip_runtime.h>
#include <cstdint>
#include <cstddef>

// ---------------------------------------------------------------------------
// SNN "CatNet" forward, MFMA v7.
// Spiking tensors: uint8 [(n*64+t), C, H, W] (exact 0/1).
// All convs run as bf16 MFMA implicit-GEMM with hi/lo split weights.
// v7 = v5 conv structure (single LDS buffer, 52-VGPR, TLP-hidden staging)
//  + KCH=2 (64-ci K-chunks: half the barriers/stage periods per block)
//  + fused pool+IF / pool+quantize kernels (from v6; no CF roundtrip).
// ---------------------------------------------------------------------------

typedef short short8 __attribute__((ext_vector_type(8)));   // 8 bf16
typedef float floatx4 __attribute__((ext_vector_type(4)));

__device__ __forceinline__ unsigned short f2bf_rne(float f) {
  unsigned u = __float_as_uint(f);
  return (unsigned short)((u + 0x7FFFu + ((u >> 16) & 1u)) >> 16);
}
__device__ __forceinline__ float bf2f(unsigned short h) {
  return __uint_as_float((unsigned)h << 16);
}

// ---------------------------------------------------------------------------
// Weight pre-transform (3x3 layers): W f32 [Co][Ci][3][3] -> bf16 hi/lo frags.
// frag(cot,ch,tap,cg,h) at shorts: (cot*nch+ch)*36864 + tap*4096 + cg*1024
//                                  + h*512 + lane*8      (ch in 32-ci units)
// ---------------------------------------------------------------------------
__global__ __launch_bounds__(256) void k_wxform(const float* __restrict__ Wsrc,
                                                unsigned short* __restrict__ wt,
                                                int Ci, int Co) {
  const int nch = Ci >> 5;
  const int total = (Co >> 6) * nch * 9 * 4 * 64;
  int idx = blockIdx.x * 256 + threadIdx.x;
  if (idx >= total) return;
  int lane = idx & 63;
  int t2 = idx >> 6;
  int cg = t2 & 3;
  int t3 = t2 >> 2;
  int tap = t3 % 9;
  int t4 = t3 / 9;
  int ch = t4 % nch;
  int cot = t4 / nch;
  int co = cot * 64 + cg * 16 + (lane & 15);
  int cib = ch * 32 + (lane >> 4) * 8;
  short8 vh, vl;
  #pragma unroll
  for (int j = 0; j < 8; ++j) {
    float wv = Wsrc[((size_t)co * Ci + cib + j) * 9 + tap];
    unsigned short h = f2bf_rne(wv);
    vh[j] = (short)h;
    vl[j] = (short)f2bf_rne(wv - bf2f(h));
  }
  size_t base = ((((size_t)cot * nch + ch) * 9 + tap) * 4 + cg) * 1024 + (size_t)lane * 8;
  *(short8*)&wt[base] = vh;
  *(short8*)&wt[base + 512] = vl;
}

// L1 weight transform: W f32 [128][3][3][3] -> K=32 frags, k = tap*3+ci.
__global__ __launch_bounds__(256) void k_wxform1(const float* __restrict__ Wsrc,
                                                 unsigned short* __restrict__ wt) {
  int idx = blockIdx.x * 256 + threadIdx.x;   // 512 total
  if (idx >= 512) return;
  int lane = idx & 63, cg = (idx >> 6) & 3, cot = idx >> 8;
  int co = cot * 64 + cg * 16 + (lane & 15);
  short8 vh, vl;
  #pragma unroll
  for (int e = 0; e < 8; ++e) {
    int k = (lane >> 4) * 8 + e;
    float wv = 0.f;
    if (k < 27) { int tap = k / 3, ci = k - 3 * tap; wv = Wsrc[(co * 3 + ci) * 9 + tap]; }
    unsigned short h = f2bf_rne(wv);
    vh[e] = (short)h;
    vl[e] = (short)f2bf_rne(wv - bf2f(h));
  }
  size_t base = (size_t)cot * 4096 + cg * 1024 + (size_t)lane * 8;
  *(short8*)&wt[base] = vh;
  *(short8*)&wt[base + 512] = vl;
}

// Transpose+pack x: [n][c][hw][t] f32 -> XT2[(n*64+t)][c][hw] u32 = hi|lo<<16
__global__ __launch_bounds__(256) void k_tpack(const float* __restrict__ x,
                                               unsigned* __restrict__ XT2) {
  int idx = blockIdx.x * 256 + threadIdx.x;   // 786432
  int b = idx / 3072;
  int rem = idx - b * 3072;
  int t = b & 63, n = b >> 6;
  float f = x[((size_t)(n * 3072 + rem)) * 64 + t];
  unsigned short h = f2bf_rne(f);
  unsigned short l = f2bf_rne(f - bf2f(h));
  XT2[idx] = (unsigned)h | ((unsigned)l << 16);
}

__global__ __launch_bounds__(256) void k_xbar_pack(const float* __restrict__ x,
                                                   unsigned* __restrict__ xb) {
  int idx = blockIdx.x * 256 + threadIdx.x;   // 12288
  if (idx >= 12288) return;
  const float* p = x + (size_t)idx * 64;
  float s = 0.f;
  #pragma unroll
  for (int t = 0; t < 64; ++t) s += p[t];
  s *= 0.015625f;
  unsigned short h = f2bf_rne(s);
  unsigned short l = f2bf_rne(s - bf2f(h));
  xb[idx] = (unsigned)h | ((unsigned)l << 16);
}

// ---------------------------------------------------------------------------
// MFMA conv, generic 3x3. PAD0=false: pad=1 square W; PAD0=true: L7 (4x4->2x2).
// Block: 256 thr / 4 waves; wave-tile 64co x (G*16)px. A from global (per-step
// double buffer), B from LDS. KCH = ci-chunks (32 ci) staged per barrier.
// grid.z = K-split: chunks [z*nchPer, (z+1)*nchPer) in KCH-units,
// out += z*osplit, bias added only by z==0.
// ---------------------------------------------------------------------------
template <typename T, bool PAD0, int G, int KCH>
__global__ __launch_bounds__(256, 1) void k_cmfma(
    const T* __restrict__ in, const unsigned short* __restrict__ wt,
    const float* __restrict__ bs, float* __restrict__ out,
    int Ci, int Co, int W, int TRI, int tpi, int NIMG, int nImgValid,
    int nchPer, size_t osplit) {
  constexpr int MT = 4 * G * 16;             // block m-tile
  constexpr int PPXMAX = PAD0 ? (MT / 4) * 16 : 208;
  constexpr int STR = KCH * 32 + 8;          // LDS row stride (shorts)
  __shared__ unsigned short sIn[PPXMAX * STR];
  const int tid = threadIdx.x;
  const int lane = tid & 63;
  const int wv = tid >> 6;
  const int cot = blockIdx.x;
  const int mtile = blockIdx.y;
  const int kz = blockIdx.z;
  const int nch = Ci >> 5;                   // 32-ci units (weight addressing)
  const int nchA = kz * nchPer, nchB = nchA + nchPer;   // KCH-units
  out += (size_t)kz * osplit;
  const int addBias = (kz == 0);

  int img_first, r0 = 0, PPR, PPX;
  if constexpr (PAD0) {
    img_first = mtile * (MT / 4);
    PPR = 16; PPX = (MT / 4) * 16;
  } else {
    img_first = (mtile / tpi) * NIMG;
    r0 = (mtile % tpi) * TRI;
    PPR = (TRI + 2) * (W + 2);
    PPX = NIMG * PPR;
  }
  const int TRW = TRI * W;

  // output / B-fragment mapping
  int p0[G], mimg[G], mopx[G];
  #pragma unroll
  for (int g = 0; g < G; ++g) {
    int m = wv * (G * 16) + g * 16 + (lane & 15);
    int limg;
    if constexpr (PAD0) {
      limg = m >> 2;
      int o = m & 3;
      p0[g] = limg * 16 + (o >> 1) * 4 + (o & 1);
      mopx[g] = (o >> 1) * 2 + (o & 1);
    } else {
      limg = m / TRW;
      int rm = m - limg * TRW;
      int r = rm / W, c = rm - r * W;
      p0[g] = limg * PPR + r * (W + 2) + c;
      mopx[g] = (r0 + r) * W + c;
    }
    mimg[g] = img_first + limg;
  }
  int psh[9];
  #pragma unroll
  for (int t = 0; t < 9; ++t) {
    int dh = t / 3, dw = t - dh * 3;
    psh[t] = PAD0 ? (dh * 4 + dw) : (dh * (W + 2) + dw);
  }

  // staging precompute (<=2 px per thread), idiv only here
  const int HWin = PAD0 ? 16 : W * W;
  int sgofs[2]; bool svalid[2];
  #pragma unroll
  for (int i = 0; i < 2; ++i) {
    int p = tid + i * 256;
    svalid[i] = false; sgofs[i] = 0;
    if (p < PPX) {
      int limg, gpx;
      if constexpr (PAD0) {
        limg = p >> 4; gpx = p & 15;
      } else {
        limg = p / PPR;
        int rem = p - limg * PPR;
        int pr = rem / (W + 2), pc = rem - pr * (W + 2);
        int gr = r0 + pr - 1, gc = pc - 1;
        gpx = (gr >= 0 && gr < W && gc >= 0 && gc < W) ? gr * W + gc : -1;
      }
      int img = img_first + limg;
      if (gpx >= 0 && img < nImgValid) {
        svalid[i] = true;
        sgofs[i] = img * Ci * HWin + gpx;
      }
    }
  }
  const int kb = (lane >> 4) * 8;

  floatx4 acc[4][G];
  floatx4 zero = {0.f, 0.f, 0.f, 0.f};
  #pragma unroll
  for (int cg = 0; cg < 4; ++cg)
    #pragma unroll
    for (int g = 0; g < G; ++g) acc[cg][g] = zero;

  for (int c2 = nchA; c2 < nchB; ++c2) {
    const int ci0 = c2 * (KCH * 32);
    // ---- stage input patch [px][KCH*32 ci] as bf16, packed b128 writes ----
    #pragma unroll
    for (int i = 0; i < 2; ++i) {
      int p = tid + i * 256;
      if (p < PPX) {
        unsigned short* dst = &sIn[p * STR];
        if (svalid[i]) {
          const T* sp = in + sgofs[i] + (size_t)ci0 * HWin;
          #pragma unroll
          for (int j = 0; j < KCH * 4; ++j) {
            short8 v;
            #pragma unroll
            for (int e = 0; e < 8; ++e) {
              if constexpr (sizeof(T) == 1)
                v[e] = sp[(size_t)(j * 8 + e) * HWin] ? (short)0x3F80 : (short)0;
              else
                v[e] = (short)f2bf_rne(((const float*)sp)[(size_t)(j * 8 + e) * HWin]);
            }
            *(short8*)&dst[j * 8] = v;
          }
        } else {
          short8 z = {};
          #pragma unroll
          for (int j = 0; j < KCH * 4; ++j) *(short8*)&dst[j * 8] = z;
        }
      }
    }
    __syncthreads();
    // ---- steps: (s, tap) flattened; A from global (double-buffered) ----
    const unsigned short* wbase = wt + ((size_t)(cot * nch + c2 * KCH)) * 36864 + (size_t)lane * 8;
    constexpr int ST = 9 * KCH;
    short8 A[2][8];
    #pragma unroll
    for (int f = 0; f < 8; ++f)
      A[0][f] = *(const short8*)(wbase + (f >> 1) * 1024 + (f & 1) * 512);
    #pragma unroll
    for (int st = 0; st < ST; ++st) {
      const int cur = st & 1;
      if (st + 1 < ST) {
        const int s1 = (st + 1) / 9, t1 = (st + 1) % 9;
        const unsigned short* wp = wbase + (size_t)s1 * 36864 + (size_t)t1 * 4096;
        #pragma unroll
        for (int f = 0; f < 8; ++f)
          A[cur ^ 1][f] = *(const short8*)(wp + (f >> 1) * 1024 + (f & 1) * 512);
      }
      const int s = st / 9, tap = st % 9;
      short8 b[G];
      #pragma unroll
      for (int g = 0; g < G; ++g)
        b[g] = *(const short8*)&sIn[(p0[g] + psh[tap]) * STR + s * 32 + kb];
      #pragma unroll
      for (int cg = 0; cg < 4; ++cg) {
        #pragma unroll
        for (int g = 0; g < G; ++g) {
          acc[cg][g] = __builtin_amdgcn_mfma_f32_16x16x32_bf16(A[cur][cg * 2 + 0], b[g], acc[cg][g], 0, 0, 0);
          acc[cg][g] = __builtin_amdgcn_mfma_f32_16x16x32_bf16(A[cur][cg * 2 + 1], b[g], acc[cg][g], 0, 0, 0);
        }
      }
    }
    __syncthreads();
  }
  // ---- epilogue: row=(lane>>4)*4+i -> co, col=lane&15 -> px ----
  const int HWout = PAD0 ? 4 : W * W;
  #pragma unroll
  for (int g = 0; g < G; ++g) {
    if (mimg[g] >= nImgValid) continue;
    #pragma unroll
    for (int cg = 0; cg < 4; ++cg) {
      #pragma unroll
      for (int i2 = 0; i2 < 4; ++i2) {
        int co = cot * 64 + cg * 16 + (lane >> 4) * 4 + i2;
        float bv = addBias ? bs[co] : 0.f;
        out[((size_t)mimg[g] * Co + co) * HWout + mopx[g]] = acc[cg][g][i2] + bv;
      }
    }
  }
}

// ---------------------------------------------------------------------------
// L1 MFMA conv: K=32 im2col (k=tap*3+ci), input packed hi/lo u32.
// ---------------------------------------------------------------------------
__global__ __launch_bounds__(256, 1) void k_l1(const unsigned* __restrict__ xin,
                                               const unsigned short* __restrict__ wt,
                                               const float* __restrict__ bs,
                                               float* __restrict__ out,
                                               int nImgValid) {
  __shared__ unsigned short sIn[256 * 72];   // [m][hi(32) | lo(32)], stride 72
  const int tid = threadIdx.x, lane = tid & 63, wv = tid >> 6;
  const int cot = blockIdx.x, mtile = blockIdx.y;
  const int img = mtile >> 2;
  const int r0 = (mtile & 3) * 8;
  {
    int m = tid;
    int r = r0 + (m >> 5), c = m & 31;
    const unsigned* ip = xin + (size_t)img * 3072;
    unsigned v[9][3];
    bool iv = (img < nImgValid);
    #pragma unroll
    for (int dh = 0; dh < 3; ++dh) {
      #pragma unroll
      for (int dw = 0; dw < 3; ++dw) {
        int rr = r + dh - 1, cc = c + dw - 1;
        bool ok = iv && rr >= 0 && rr < 32 && cc >= 0 && cc < 32;
        #pragma unroll
        for (int ci = 0; ci < 3; ++ci)
          v[dh * 3 + dw][ci] = ok ? ip[ci * 1024 + rr * 32 + cc] : 0u;
      }
    }
    #pragma unroll
    for (int j = 0; j < 4; ++j) {
      short8 vh, vl;
      #pragma unroll
      for (int e = 0; e < 8; ++e) {
        int k = j * 8 + e;
        unsigned u = (k < 27) ? v[k / 3][k - 3 * (k / 3)] : 0u;
        vh[e] = (short)(u & 0xFFFFu);
        vl[e] = (short)(u >> 16);
      }
      *(short8*)&sIn[m * 72 + j * 8] = vh;
      *(short8*)&sIn[m * 72 + 32 + j * 8] = vl;
    }
  }
  __syncthreads();
  const int kb = (lane >> 4) * 8;
  const unsigned short* wb = wt + (size_t)cot * 4096 + (size_t)lane * 8;
  short8 Af[8];
  #pragma unroll
  for (int f = 0; f < 8; ++f)
    Af[f] = *(const short8*)(wb + (f >> 1) * 1024 + (f & 1) * 512);
  floatx4 acc[4][4];
  floatx4 zero = {0.f, 0.f, 0.f, 0.f};
  #pragma unroll
  for (int cg = 0; cg < 4; ++cg)
    #pragma unroll
    for (int g = 0; g < 4; ++g) acc[cg][g] = zero;
  short8 bh[4], bl[4];
  #pragma unroll
  for (int g = 0; g < 4; ++g) {
    int m = wv * 64 + g * 16 + (lane & 15);
    bh[g] = *(const short8*)&sIn[m * 72 + kb];
    bl[g] = *(const short8*)&sIn[m * 72 + 32 + kb];
  }
  #pragma unroll
  for (int cg = 0; cg < 4; ++cg) {
    #pragma unroll
    for (int g = 0; g < 4; ++g) {
      acc[cg][g] = __builtin_amdgcn_mfma_f32_16x16x32_bf16(Af[cg * 2 + 0], bh[g], acc[cg][g], 0, 0, 0);
      acc[cg][g] = __builtin_amdgcn_mfma_f32_16x16x32_bf16(Af[cg * 2 + 0], bl[g], acc[cg][g], 0, 0, 0);
      acc[cg][g] = __builtin_amdgcn_mfma_f32_16x16x32_bf16(Af[cg * 2 + 1], bh[g], acc[cg][g], 0, 0, 0);
    }
  }
  if (img >= nImgValid) return;
  #pragma unroll
  for (int g = 0; g < 4; ++g) {
    int mbase = wv * 64 + g * 16 + (lane & 15);
    int px = (r0 + (mbase >> 5)) * 32 + (mbase & 31);
    #pragma unroll
    for (int cg = 0; cg < 4; ++cg) {
      #pragma unroll
      for (int i2 = 0; i2 < 4; ++i2) {
        int co = cot * 64 + cg * 16 + (lane >> 4) * 4 + i2;
        out[((size_t)img * 128 + co) * 1024 + px] = acc[cg][g][i2] + bs[co];
      }
    }
  }
}

// ---------------------------------------------------------------------------
// Integrate-and-fire; blockIdx.y = 64-t group. Sums nparts partials.
__global__ __launch_bounds__(256) void k_if(const float* __restrict__ X,
                                            uint8_t* __restrict__ Sp,
                                            const float* __restrict__ th,
                                            float* __restrict__ ssum,
                                            int C, int HW,
                                            int nparts, size_t pstride) {
  const int CHW = C * HW;
  int idx = blockIdx.x * 256 + threadIdx.x;
  if (idx >= CHW) return;
  int c = idx / HW;
  const float thv = th[c];
  size_t base = (size_t)blockIdx.y * 64 * CHW + idx;
  const float* p = X + base;
  uint8_t* q = Sp + base;
  float v = 0.f, ss = 0.f;
  #pragma unroll
  for (int t = 0; t < 64; ++t) {
    const float* pt = p + (size_t)t * CHW;
    float xv = pt[0];
    for (int u = 1; u < nparts; ++u) xv += pt[(size_t)u * pstride];
    v += xv;
    float s = (v >= thv) ? 1.f : 0.f;
    v -= s * thv;
    q[(size_t)t * CHW] = (uint8_t)s;
    ss += s;
  }
  if ((HW & 63) == 0) {
    for (int off = 32; off >= 1; off >>= 1) ss += __shfl_down(ss, off);
    if ((threadIdx.x & 63) == 0) atomicAdd(&ssum[c], ss);
  } else {
    atomicAdd(&ssum[c], ss);
  }
}

// Fused 2x2 avg-pool + integrate-and-fire on uint8 spikes.
__global__ __launch_bounds__(256) void k_ifpool(const uint8_t* __restrict__ Sin,
                                                uint8_t* __restrict__ Sp,
                                                const float* __restrict__ th,
                                                float* __restrict__ ssum,
                                                float* __restrict__ Sout,
                                                int C, int H) {
  const int Ho = H >> 1, HWo = Ho * Ho;
  const int CHWo = C * HWo;
  int idx = blockIdx.x * 256 + threadIdx.x;
  if (idx >= CHWo) return;
  int c = idx / HWo;
  int rem = idx - c * HWo;
  int ho = rem / Ho, wo = rem - ho * Ho;
  const float thv = th[c];
  const size_t istep = (size_t)C * H * H;
  const size_t ib = ((size_t)(blockIdx.y * 64) * C + c) * (H * H) + (2 * ho) * H + 2 * wo;
  uint8_t* q = Sp + (size_t)blockIdx.y * 64 * CHWo + idx;
  float v = 0.f, ss = 0.f;
  #pragma unroll
  for (int t = 0; t < 64; ++t) {
    const uint8_t* pp = Sin + ib + (size_t)t * istep;
    float xv = 0.25f * ((float)pp[0] + (float)pp[1] + (float)pp[H] + (float)pp[H + 1]);
    v += xv;
    float s = (v >= thv) ? 1.f : 0.f;
    v -= s * thv;
    q[(size_t)t * CHWo] = (uint8_t)s;
    ss += s;
  }
  if (Sout && HWo == 1) Sout[blockIdx.y * C + c] = ss;
  if ((HWo & 63) == 0) {
    for (int off = 32; off >= 1; off >>= 1) ss += __shfl_down(ss, off);
    if ((threadIdx.x & 63) == 0) atomicAdd(&ssum[c], ss);
  } else {
    atomicAdd(&ssum[c], ss);
  }
}

// Fused 2x2 avg-pool + quantize on analog path (batch 4).
__global__ __launch_bounds__(256) void k_ttypool(const float* __restrict__ yin,
                                                 float* __restrict__ yout,
                                                 float* __restrict__ ysum,
                                                 int C, int H) {
  const int Ho = H >> 1, HWo = Ho * Ho;
  int idx = blockIdx.x * 256 + threadIdx.x;
  if (idx >= 4 * C * HWo) return;
  int rem = idx % (C * HWo);
  int c = rem / HWo;
  int r2 = rem - c * HWo;
  int ho = r2 / Ho, wo = r2 - ho * Ho;
  int img = idx / (C * HWo);
  size_t base = (((size_t)img * C + c) * H + 2 * ho) * H + 2 * wo;
  float xv = 0.25f * (yin[base] + yin[base + 1] + yin[base + H] + yin[base + H + 1]);
  float v = floorf(xv * 64.f) * 0.015625f;
  v = fminf(fmaxf(v, 0.f), 1.f);
  yout[idx] = v;
  if ((HWo & 63) == 0) {
    for (int off = 32; off >= 1; off >>= 1) v += __shfl_down(v, off);
    if ((threadIdx.x & 63) == 0) atomicAdd(&ysum[c], v);
  } else {
    atomicAdd(&ysum[c], v);
  }
}

// Analog quantize; sums nparts partial conv outputs (K-split) first.
__global__ __launch_bounds__(256) void k_tty(const float* __restrict__ y4,
                                             float* __restrict__ yout,
                                             float* __restrict__ ysum,
                                             int C, int HW,
                                             int nparts, int pstride) {
  int idx = blockIdx.x * 256 + threadIdx.x;
  if (idx >= 4 * C * HW) return;
  int rem = idx % (C * HW);
  int c = rem / HW;
  float xv = 0.f;
  for (int p = 0; p < nparts; ++p) xv += y4[idx + (size_t)p * pstride];
  float v = floorf(xv * 64.f) * 0.015625f;
  v = fminf(fmaxf(v, 0.f), 1.f);
  yout[idx] = v;
  if ((HW & 63) == 0) {
    for (int off = 32; off >= 1; off >>= 1) v += __shfl_down(v, off);
    if ((threadIdx.x & 63) == 0) atomicAdd(&ysum[c], v);
  } else {
    atomicAdd(&ysum[c], v);
  }
}

__global__ void k_thr(const float* __restrict__ thin,
                      const float* __restrict__ ssum,
                      const float* __restrict__ ysum,
                      float* __restrict__ dst, int C, float invmul) {
  int c = blockIdx.x * 256 + threadIdx.x;
  if (c >= C) return;
  float diff = (ysum[c] * 64.f - ssum[c]) * invmul;
  dst[c] = thin[c] - 0.1f * diff;
}

__global__ void k_cls(const float* __restrict__ S, const float* __restrict__ wc,
                      const float* __restrict__ bcp, float* __restrict__ out) {
  int idx = blockIdx.x * 256 + threadIdx.x;
  if (idx >= 400) return;
  int n = idx / 100, o = idx - (idx / 100) * 100;
  const float* sp = S + n * 1024;
  const float* wp = wc + o * 1024;
  float acc = 0.f;
  for (int c = 0; c < 1024; ++c) acc += wp[c] * sp[c];
  out[idx] = acc * 0.015625f + bcp[o];
}

extern "C" void kernel_launch(void* const* d_in, const int* in_sizes, int n_in,
                              void* d_out_v, int out_size, void* d_ws, size_t ws_size,
                              hipStream_t stream) {
  const float *Ws[7], *Bs[7], *Wa[7], *Ba[7];
  for (int i = 0; i < 7; ++i) {
    Ws[i] = (const float*)d_in[i * 4 + 0];
    Bs[i] = (const float*)d_in[i * 4 + 1];
    Wa[i] = (const float*)d_in[i * 4 + 2];
    Ba[i] = (const float*)d_in[i * 4 + 3];
  }
  const float* wc = (const float*)d_in[28];
  const float* bc = (const float*)d_in[29];
  const float* x  = (const float*)d_in[30];
  const float* TH[7];
  for (int i = 0; i < 7; ++i) TH[i] = (const float*)d_in[31 + i];
  const float* P[4];
  for (int i = 0; i < 4; ++i) P[i] = (const float*)d_in[38 + i];
  float* out = (float*)d_out_v;

  // ---- workspace (107.7 MB) ----
  float* w = (float*)d_ws;
  const size_t RF = 8536064;      // [WT | CF0] region, per-layer split
  float* Rb = w;
  size_t off = RF;
  float* xbar = w + off; off += 12288;    // packed u32 hi/lo
  float* yA   = w + off; off += 524288;
  float* yB   = w + off; off += 524288;
  float* y4   = w + off; off += 524288;
  float* S    = w + off; off += 4096;
  float* sums = w + off; off += 11 * 2048;
  uint8_t* SA = (uint8_t*)(w + off);
  uint8_t* SB = SA + 33554432;
  size_t total_bytes = off * sizeof(float) + (size_t)2 * 33554432;
  if (ws_size < total_bytes) return;
  unsigned short* WT = (unsigned short*)Rb;
  unsigned* XT2 = (unsigned*)SB;          // aliases SB (dead until L2 output)
  unsigned* xbar2 = (unsigned*)xbar;

  hipMemsetAsync(sums, 0, 11 * 2048 * sizeof(float), stream);
  k_tpack<<<3072, 256, 0, stream>>>(x, XT2);
  k_xbar_pack<<<48, 256, 0, stream>>>(x, xbar2);

  int stage = 0;

  // ---- L1 (MFMA im2col) ----
  {
    float* CF = Rb + 4096;                 // WT1 = 16 KB
    float* ss = sums; float* ys = ss + 1024;
    k_wxform1<<<2, 256, 0, stream>>>(Ws[0], WT);
    for (int c = 0; c < 4; ++c) {
      k_l1<<<dim3(2, 256), 256, 0, stream>>>(XT2 + (size_t)c * 64 * 3072, WT, Bs[0], CF, 64);
      k_if<<<dim3(512, 1), 256, 0, stream>>>(CF, SA + (size_t)c * 64 * 131072,
                                             TH[0], ss, 128, 1024, 1, 0);
    }
    k_wxform1<<<2, 256, 0, stream>>>(Wa[0], WT);
    k_l1<<<dim3(2, 16), 256, 0, stream>>>(xbar2, WT, Ba[0], y4, 4);
    k_tty<<<2048, 256, 0, stream>>>(y4, yA, ys, 128, 1024, 1, 0);
    k_thr<<<1, 256, 0, stream>>>(TH[0], ss, ys, out + 400, 128, 1.0f / (4.f * 1024.f * 64.f));
    ++stage;
  }

  // ---- generic pad=1 MFMA layer ----
  // Spike conv: G=2/KCH=2 tile, optional kz (partials at CF1).
  // Analog conv (batch 4): G=1/KCH=2, aTRI/atpi geometry, akz K-split in y4.
  auto mfma_layer = [&](const uint8_t* inS, uint8_t* outS, const float* inY, float* outY,
                        int li, int Ci, int Co, int W, int TRI, int tpi, int NIMG,
                        int chunkImgs, int kzn, float* CF1,
                        int aTRI, int atpi, int akz,
                        const float* thin, int outoff) {
    const int HW = W * W;
    const int CHWo = Co * HW;
    const int nch = Ci >> 5;
    const int nch2 = Ci >> 6;                // KCH=2 units
    float* ss = sums + stage * 2048; float* ys = ss + 1024;
    float* CF = Rb + (size_t)Co * Ci * 9;
    size_t osplit = (kzn == 2) ? (size_t)(CF1 - CF) : 0;
    int xgrid = ((Co / 64) * nch * 9 * 4 * 64 + 255) / 256;
    k_wxform<<<xgrid, 256, 0, stream>>>(Ws[li], WT, Ci, Co);
    int nchk = 256 / chunkImgs;
    int mt = (chunkImgs / NIMG) * tpi;
    for (int c = 0; c < nchk; ++c) {
      k_cmfma<uint8_t, false, 2, 2><<<dim3(Co / 64, mt, kzn), 256, 0, stream>>>(
          inS + (size_t)c * chunkImgs * Ci * HW, WT, Bs[li], CF,
          Ci, Co, W, TRI, tpi, NIMG, chunkImgs, nch2 / kzn, osplit);
      k_if<<<dim3((CHWo + 255) / 256, chunkImgs / 64), 256, 0, stream>>>(
          CF, outS + (size_t)c * chunkImgs * CHWo, thin, ss, Co, HW, kzn, osplit);
    }
    k_wxform<<<xgrid, 256, 0, stream>>>(Wa[li], WT, Ci, Co);
    int aosplit = 4 * CHWo;
    k_cmfma<float, false, 1, 2><<<dim3(Co / 64, 4 * atpi, akz), 256, 0, stream>>>(
        inY, WT, Ba[li], y4, Ci, Co, W, aTRI, atpi, 1, 4, nch2 / akz, (size_t)aosplit);
    k_tty<<<(4 * CHWo + 255) / 256, 256, 0, stream>>>(y4, outY, ys, Co, HW, akz, aosplit);
    k_thr<<<(Co + 255) / 256, 256, 0, stream>>>(thin, ss, ys, out + outoff, Co,
                                                1.0f / (4.f * HW * 64.f));
    ++stage;
  };

  auto pool_stage = [&](const uint8_t* inS, uint8_t* outS, const float* inY, float* outY,
                        int C, int H, const float* pthr, int outoff, float* Sout) {
    const int Ho = H / 2, HWo = Ho * Ho;
    const int CHWo = C * HWo;
    float* ss = sums + stage * 2048; float* ys = ss + 1024;
    k_ifpool<<<dim3((CHWo + 255) / 256, 4), 256, 0, stream>>>(inS, outS, pthr, ss, Sout, C, H);
    k_ttypool<<<(4 * CHWo + 255) / 256, 256, 0, stream>>>(inY, outY, ys, C, H);
    k_thr<<<(C + 255) / 256, 256, 0, stream>>>(pthr, ss, ys, out + outoff, C,
                                               1.0f / (4.f * HWo * 64.f));
    ++stage;
  };

  // L2: spike TRI=4,tpi=8 -> grid(2,512,1); analog aTRI=2,atpi=16, akz=1
  mfma_layer(SA, SB, yA, yB, 1, 128, 128, 32, 4, 8, 1, 64, 1, nullptr,
             2, 16, 1, TH[1], 528);
  // P1
  pool_stage(SB, SA, yB, yA, 128, 32, P[0], 3216, nullptr);
  // L3: spike TRI=8,tpi=2, kz=2 (partial SB tail) -> grid(4,128,2)
  mfma_layer(SA, SB, yA, yB, 2, 128, 256, 16, 8, 2, 1, 64, 2,
             (float*)(SB + 16777216), 4, 4, 2, TH[2], 656);
  // L4
  mfma_layer(SB, SA, yB, yA, 3, 256, 256, 16, 8, 2, 1, 64, 2,
             (float*)(SA + 16777216), 4, 4, 2, TH[3], 912);
  // P2
  pool_stage(SA, SB, yA, yB, 256, 16, P[1], 3344, nullptr);
  // L5: spike NIMG=2,TRI=8,tpi=1, kz=2 -> grid(8,64,2)
  mfma_layer(SB, SA, yB, yA, 4, 256, 512, 8, 8, 1, 2, 128, 2,
             (float*)(SA + 8388608), 8, 1, 4, TH[4], 1168);
  // L6
  mfma_layer(SA, SB, yA, yB, 5, 512, 512, 8, 8, 1, 2, 128, 2,
             (float*)(SB + 8388608), 8, 1, 4, TH[5], 1680);
  // P3
  pool_stage(SB, SA, yB, yA, 512, 8, P[2], 3600, nullptr);
  // L7 (pad=0): spike KCH=1 kz=4, partials in SA tail; analog KCH=1 akz=8 in y4
  {
    float* ss = sums + stage * 2048; float* ys = ss + 1024;
    float* CF = (float*)(SA + 4194304);         // 4 partials x 4.2 MB
    const size_t osplit = 1048576;              // 256*1024*4 elems
    int xgrid = (16 * 16 * 9 * 4 * 64 + 255) / 256;
    k_wxform<<<xgrid, 256, 0, stream>>>(Ws[6], WT, 512, 1024);
    k_cmfma<uint8_t, true, 2, 1><<<dim3(16, 8, 4), 256, 0, stream>>>(
        SA, WT, Bs[6], CF, 512, 1024, 4, 0, 1, 0, 256, 4, osplit);
    k_if<<<dim3(16, 4), 256, 0, stream>>>(CF, SB, TH[6], ss, 1024, 4, 4, osplit);
    k_wxform<<<xgrid, 256, 0, stream>>>(Wa[6], WT, 512, 1024);
    k_cmfma<float, true, 1, 1><<<dim3(16, 1, 8), 256, 0, stream>>>(
        yA, WT, Ba[6], y4, 512, 1024, 4, 0, 1, 0, 4, 2, 16384);
    k_tty<<<64, 256, 0, stream>>>(y4, yB, ys, 1024, 4, 8, 16384);
    k_thr<<<4, 256, 0, stream>>>(TH[6], ss, ys, out + 2192, 1024, 1.0f / 1024.f);
    ++stage;
  }
  // P4: fused pool+IF also writes S directly
  pool_stage(SB, SA, yB, yA, 1024, 2, P[3], 4112, S);
  // classifier
  k_cls<<<2, 256, 0, stream>>>(S, wc, bc, out);
}

// Round 13
// 1999.267 us; speedup vs baseline: 1.2804x; 1.0160x over previous
//
#include <hip/hip_runtime.h>
#include <cstdint>
#include <cstddef>

// ---------------------------------------------------------------------------
// SNN "CatNet" forward, MFMA v8.
// Spiking tensors: uint8 [(n*64+t), C, H, W] (exact 0/1).
// All convs run as bf16 MFMA implicit-GEMM with hi/lo split weights.
// v8: waves co-split (wave wv owns cg=wv; all waves share the px tile) ->
// A-fragment global reads are disjoint per wave (4x less L2 traffic).
// KCH=1 (v5-proven), fused pool+IF / pool+quantize kernels.
// ---------------------------------------------------------------------------

typedef short short8 __attribute__((ext_vector_type(8)));   // 8 bf16
typedef float floatx4 __attribute__((ext_vector_type(4)));

__device__ __forceinline__ unsigned short f2bf_rne(float f) {
  unsigned u = __float_as_uint(f);
  return (unsigned short)((u + 0x7FFFu + ((u >> 16) & 1u)) >> 16);
}
__device__ __forceinline__ float bf2f(unsigned short h) {
  return __uint_as_float((unsigned)h << 16);
}

// ---------------------------------------------------------------------------
// Weight pre-transform (3x3 layers): W f32 [Co][Ci][3][3] -> bf16 hi/lo frags.
// frag(cot,ch,tap,cg,h) at shorts: (cot*nch+ch)*36864 + tap*4096 + cg*1024
//                                  + h*512 + lane*8      (ch in 32-ci units)
// ---------------------------------------------------------------------------
__global__ __launch_bounds__(256) void k_wxform(const float* __restrict__ Wsrc,
                                                unsigned short* __restrict__ wt,
                                                int Ci, int Co) {
  const int nch = Ci >> 5;
  const int total = (Co >> 6) * nch * 9 * 4 * 64;
  int idx = blockIdx.x * 256 + threadIdx.x;
  if (idx >= total) return;
  int lane = idx & 63;
  int t2 = idx >> 6;
  int cg = t2 & 3;
  int t3 = t2 >> 2;
  int tap = t3 % 9;
  int t4 = t3 / 9;
  int ch = t4 % nch;
  int cot = t4 / nch;
  int co = cot * 64 + cg * 16 + (lane & 15);
  int cib = ch * 32 + (lane >> 4) * 8;
  short8 vh, vl;
  #pragma unroll
  for (int j = 0; j < 8; ++j) {
    float wv = Wsrc[((size_t)co * Ci + cib + j) * 9 + tap];
    unsigned short h = f2bf_rne(wv);
    vh[j] = (short)h;
    vl[j] = (short)f2bf_rne(wv - bf2f(h));
  }
  size_t base = ((((size_t)cot * nch + ch) * 9 + tap) * 4 + cg) * 1024 + (size_t)lane * 8;
  *(short8*)&wt[base] = vh;
  *(short8*)&wt[base + 512] = vl;
}

// L1 weight transform: W f32 [128][3][3][3] -> K=32 frags, k = tap*3+ci.
__global__ __launch_bounds__(256) void k_wxform1(const float* __restrict__ Wsrc,
                                                 unsigned short* __restrict__ wt) {
  int idx = blockIdx.x * 256 + threadIdx.x;   // 512 total
  if (idx >= 512) return;
  int lane = idx & 63, cg = (idx >> 6) & 3, cot = idx >> 8;
  int co = cot * 64 + cg * 16 + (lane & 15);
  short8 vh, vl;
  #pragma unroll
  for (int e = 0; e < 8; ++e) {
    int k = (lane >> 4) * 8 + e;
    float wv = 0.f;
    if (k < 27) { int tap = k / 3, ci = k - 3 * tap; wv = Wsrc[(co * 3 + ci) * 9 + tap]; }
    unsigned short h = f2bf_rne(wv);
    vh[e] = (short)h;
    vl[e] = (short)f2bf_rne(wv - bf2f(h));
  }
  size_t base = (size_t)cot * 4096 + cg * 1024 + (size_t)lane * 8;
  *(short8*)&wt[base] = vh;
  *(short8*)&wt[base + 512] = vl;
}

// Transpose+pack x: [n][c][hw][t] f32 -> XT2[(n*64+t)][c][hw] u32 = hi|lo<<16
__global__ __launch_bounds__(256) void k_tpack(const float* __restrict__ x,
                                               unsigned* __restrict__ XT2) {
  int idx = blockIdx.x * 256 + threadIdx.x;   // 786432
  int b = idx / 3072;
  int rem = idx - b * 3072;
  int t = b & 63, n = b >> 6;
  float f = x[((size_t)(n * 3072 + rem)) * 64 + t];
  unsigned short h = f2bf_rne(f);
  unsigned short l = f2bf_rne(f - bf2f(h));
  XT2[idx] = (unsigned)h | ((unsigned)l << 16);
}

__global__ __launch_bounds__(256) void k_xbar_pack(const float* __restrict__ x,
                                                   unsigned* __restrict__ xb) {
  int idx = blockIdx.x * 256 + threadIdx.x;   // 12288
  if (idx >= 12288) return;
  const float* p = x + (size_t)idx * 64;
  float s = 0.f;
  #pragma unroll
  for (int t = 0; t < 64; ++t) s += p[t];
  s *= 0.015625f;
  unsigned short h = f2bf_rne(s);
  unsigned short l = f2bf_rne(s - bf2f(h));
  xb[idx] = (unsigned)h | ((unsigned)l << 16);
}

// ---------------------------------------------------------------------------
// MFMA conv, generic 3x3. PAD0=false: pad=1 square W; PAD0=true: L7 (4x4->2x2).
// Block: 256 thr / 4 waves. CO-SPLIT: wave wv computes cg=wv (16 co) over the
// block's WHOLE px tile MT = G*16. A (2 frags hi/lo per step) from global,
// disjoint per wave; B from LDS (stride-40-short rows).
// grid.z = K-split: 32-ci chunks [z*nchPer, (z+1)*nchPer), out += z*osplit,
// bias added only by z==0.
// ---------------------------------------------------------------------------
template <typename T, bool PAD0, int G, int KCH>
__global__ __launch_bounds__(256, 1) void k_cmfma(
    const T* __restrict__ in, const unsigned short* __restrict__ wt,
    const float* __restrict__ bs, float* __restrict__ out,
    int Ci, int Co, int W, int TRI, int tpi, int NIMG, int nImgValid,
    int nchPer, size_t osplit) {
  constexpr int MT = G * 16;                 // block m-tile (all waves share)
  constexpr int PPXMAX = PAD0 ? (MT / 4) * 16 : 208;
  constexpr int STR = KCH * 32 + 8;          // LDS row stride (shorts)
  __shared__ unsigned short sIn[PPXMAX * STR];
  const int tid = threadIdx.x;
  const int lane = tid & 63;
  const int wv = tid >> 6;                   // = cg
  const int cot = blockIdx.x;
  const int mtile = blockIdx.y;
  const int kz = blockIdx.z;
  const int nch = Ci >> 5;
  const int nchA = kz * nchPer, nchB = nchA + nchPer;   // KCH-units
  out += (size_t)kz * osplit;
  const int addBias = (kz == 0);

  int img_first, r0 = 0, PPR, PPX;
  if constexpr (PAD0) {
    img_first = mtile * (MT / 4);
    PPR = 16; PPX = (MT / 4) * 16;
  } else {
    img_first = (mtile / tpi) * NIMG;
    r0 = (mtile % tpi) * TRI;
    PPR = (TRI + 2) * (W + 2);
    PPX = NIMG * PPR;
  }
  const int TRW = TRI * W;

  // output / B-fragment mapping: m = g*16 + (lane&15), shared by all waves
  int p0[G], mimg[G], mopx[G];
  #pragma unroll
  for (int g = 0; g < G; ++g) {
    int m = g * 16 + (lane & 15);
    int limg;
    if constexpr (PAD0) {
      limg = m >> 2;
      int o = m & 3;
      p0[g] = limg * 16 + (o >> 1) * 4 + (o & 1);
      mopx[g] = (o >> 1) * 2 + (o & 1);
    } else {
      limg = m / TRW;
      int rm = m - limg * TRW;
      int r = rm / W, c = rm - r * W;
      p0[g] = limg * PPR + r * (W + 2) + c;
      mopx[g] = (r0 + r) * W + c;
    }
    mimg[g] = img_first + limg;
  }
  int psh[9];
  #pragma unroll
  for (int t = 0; t < 9; ++t) {
    int dh = t / 3, dw = t - dh * 3;
    psh[t] = PAD0 ? (dh * 4 + dw) : (dh * (W + 2) + dw);
  }

  // staging precompute (<=2 px per thread), idiv only here
  const int HWin = PAD0 ? 16 : W * W;
  int sgofs[2]; bool svalid[2];
  #pragma unroll
  for (int i = 0; i < 2; ++i) {
    int p = tid + i * 256;
    svalid[i] = false; sgofs[i] = 0;
    if (p < PPX) {
      int limg, gpx;
      if constexpr (PAD0) {
        limg = p >> 4; gpx = p & 15;
      } else {
        limg = p / PPR;
        int rem = p - limg * PPR;
        int pr = rem / (W + 2), pc = rem - pr * (W + 2);
        int gr = r0 + pr - 1, gc = pc - 1;
        gpx = (gr >= 0 && gr < W && gc >= 0 && gc < W) ? gr * W + gc : -1;
      }
      int img = img_first + limg;
      if (gpx >= 0 && img < nImgValid) {
        svalid[i] = true;
        sgofs[i] = img * Ci * HWin + gpx;
      }
    }
  }
  const int kb = (lane >> 4) * 8;

  floatx4 acc[G];
  floatx4 zero = {0.f, 0.f, 0.f, 0.f};
  #pragma unroll
  for (int g = 0; g < G; ++g) acc[g] = zero;

  for (int c2 = nchA; c2 < nchB; ++c2) {
    const int ci0 = c2 * (KCH * 32);
    // ---- stage input patch [px][KCH*32 ci] as bf16, packed b128 writes ----
    #pragma unroll
    for (int i = 0; i < 2; ++i) {
      int p = tid + i * 256;
      if (p < PPX) {
        unsigned short* dst = &sIn[p * STR];
        if (svalid[i]) {
          const T* sp = in + sgofs[i] + (size_t)ci0 * HWin;
          #pragma unroll
          for (int j = 0; j < KCH * 4; ++j) {
            short8 v;
            #pragma unroll
            for (int e = 0; e < 8; ++e) {
              if constexpr (sizeof(T) == 1)
                v[e] = sp[(size_t)(j * 8 + e) * HWin] ? (short)0x3F80 : (short)0;
              else
                v[e] = (short)f2bf_rne(((const float*)sp)[(size_t)(j * 8 + e) * HWin]);
            }
            *(short8*)&dst[j * 8] = v;
          }
        } else {
          short8 z = {};
          #pragma unroll
          for (int j = 0; j < KCH * 4; ++j) *(short8*)&dst[j * 8] = z;
        }
      }
    }
    __syncthreads();
    // ---- steps: (s, tap); A = this wave's cg slice (hi/lo), double-buffered
    const unsigned short* wbase = wt + ((size_t)(cot * nch + c2 * KCH)) * 36864
                                  + (size_t)wv * 1024 + (size_t)lane * 8;
    constexpr int ST = 9 * KCH;
    short8 A[2][2];
    A[0][0] = *(const short8*)(wbase);
    A[0][1] = *(const short8*)(wbase + 512);
    #pragma unroll
    for (int st = 0; st < ST; ++st) {
      const int cur = st & 1;
      if (st + 1 < ST) {
        const int s1 = (st + 1) / 9, t1 = (st + 1) % 9;
        const unsigned short* wp = wbase + (size_t)s1 * 36864 + (size_t)t1 * 4096;
        A[cur ^ 1][0] = *(const short8*)(wp);
        A[cur ^ 1][1] = *(const short8*)(wp + 512);
      }
      const int s = st / 9, tap = st % 9;
      short8 b[G];
      #pragma unroll
      for (int g = 0; g < G; ++g)
        b[g] = *(const short8*)&sIn[(p0[g] + psh[tap]) * STR + s * 32 + kb];
      #pragma unroll
      for (int g = 0; g < G; ++g) {
        acc[g] = __builtin_amdgcn_mfma_f32_16x16x32_bf16(A[cur][0], b[g], acc[g], 0, 0, 0);
        acc[g] = __builtin_amdgcn_mfma_f32_16x16x32_bf16(A[cur][1], b[g], acc[g], 0, 0, 0);
      }
    }
    __syncthreads();
  }
  // ---- epilogue: co = cot*64 + wv*16 + (lane>>4)*4 + i2, px = mopx[g] ----
  const int HWout = PAD0 ? 4 : W * W;
  #pragma unroll
  for (int g = 0; g < G; ++g) {
    if (mimg[g] >= nImgValid) continue;
    #pragma unroll
    for (int i2 = 0; i2 < 4; ++i2) {
      int co = cot * 64 + wv * 16 + (lane >> 4) * 4 + i2;
      float bv = addBias ? bs[co] : 0.f;
      out[((size_t)mimg[g] * Co + co) * HWout + mopx[g]] = acc[g][i2] + bv;
    }
  }
}

// ---------------------------------------------------------------------------
// L1 MFMA conv: K=32 im2col (k=tap*3+ci), input packed hi/lo u32.
// ---------------------------------------------------------------------------
__global__ __launch_bounds__(256, 1) void k_l1(const unsigned* __restrict__ xin,
                                               const unsigned short* __restrict__ wt,
                                               const float* __restrict__ bs,
                                               float* __restrict__ out,
                                               int nImgValid) {
  __shared__ unsigned short sIn[256 * 72];   // [m][hi(32) | lo(32)], stride 72
  const int tid = threadIdx.x, lane = tid & 63, wv = tid >> 6;
  const int cot = blockIdx.x, mtile = blockIdx.y;
  const int img = mtile >> 2;
  const int r0 = (mtile & 3) * 8;
  {
    int m = tid;
    int r = r0 + (m >> 5), c = m & 31;
    const unsigned* ip = xin + (size_t)img * 3072;
    unsigned v[9][3];
    bool iv = (img < nImgValid);
    #pragma unroll
    for (int dh = 0; dh < 3; ++dh) {
      #pragma unroll
      for (int dw = 0; dw < 3; ++dw) {
        int rr = r + dh - 1, cc = c + dw - 1;
        bool ok = iv && rr >= 0 && rr < 32 && cc >= 0 && cc < 32;
        #pragma unroll
        for (int ci = 0; ci < 3; ++ci)
          v[dh * 3 + dw][ci] = ok ? ip[ci * 1024 + rr * 32 + cc] : 0u;
      }
    }
    #pragma unroll
    for (int j = 0; j < 4; ++j) {
      short8 vh, vl;
      #pragma unroll
      for (int e = 0; e < 8; ++e) {
        int k = j * 8 + e;
        unsigned u = (k < 27) ? v[k / 3][k - 3 * (k / 3)] : 0u;
        vh[e] = (short)(u & 0xFFFFu);
        vl[e] = (short)(u >> 16);
      }
      *(short8*)&sIn[m * 72 + j * 8] = vh;
      *(short8*)&sIn[m * 72 + 32 + j * 8] = vl;
    }
  }
  __syncthreads();
  const int kb = (lane >> 4) * 8;
  const unsigned short* wb = wt + (size_t)cot * 4096 + (size_t)lane * 8;
  short8 Af[8];
  #pragma unroll
  for (int f = 0; f < 8; ++f)
    Af[f] = *(const short8*)(wb + (f >> 1) * 1024 + (f & 1) * 512);
  floatx4 acc[4][4];
  floatx4 zero = {0.f, 0.f, 0.f, 0.f};
  #pragma unroll
  for (int cg = 0; cg < 4; ++cg)
    #pragma unroll
    for (int g = 0; g < 4; ++g) acc[cg][g] = zero;
  short8 bh[4], bl[4];
  #pragma unroll
  for (int g = 0; g < 4; ++g) {
    int m = wv * 64 + g * 16 + (lane & 15);
    bh[g] = *(const short8*)&sIn[m * 72 + kb];
    bl[g] = *(const short8*)&sIn[m * 72 + 32 + kb];
  }
  #pragma unroll
  for (int cg = 0; cg < 4; ++cg) {
    #pragma unroll
    for (int g = 0; g < 4; ++g) {
      acc[cg][g] = __builtin_amdgcn_mfma_f32_16x16x32_bf16(Af[cg * 2 + 0], bh[g], acc[cg][g], 0, 0, 0);
      acc[cg][g] = __builtin_amdgcn_mfma_f32_16x16x32_bf16(Af[cg * 2 + 0], bl[g], acc[cg][g], 0, 0, 0);
      acc[cg][g] = __builtin_amdgcn_mfma_f32_16x16x32_bf16(Af[cg * 2 + 1], bh[g], acc[cg][g], 0, 0, 0);
    }
  }
  if (img >= nImgValid) return;
  #pragma unroll
  for (int g = 0; g < 4; ++g) {
    int mbase = wv * 64 + g * 16 + (lane & 15);
    int px = (r0 + (mbase >> 5)) * 32 + (mbase & 31);
    #pragma unroll
    for (int cg = 0; cg < 4; ++cg) {
      #pragma unroll
      for (int i2 = 0; i2 < 4; ++i2) {
        int co = cot * 64 + cg * 16 + (lane >> 4) * 4 + i2;
        out[((size_t)img * 128 + co) * 1024 + px] = acc[cg][g][i2] + bs[co];
      }
    }
  }
}

// ---------------------------------------------------------------------------
// Integrate-and-fire; blockIdx.y = 64-t group. Sums nparts partials.
__global__ __launch_bounds__(256) void k_if(const float* __restrict__ X,
                                            uint8_t* __restrict__ Sp,
                                            const float* __restrict__ th,
                                            float* __restrict__ ssum,
                                            int C, int HW,
                                            int nparts, size_t pstride) {
  const int CHW = C * HW;
  int idx = blockIdx.x * 256 + threadIdx.x;
  if (idx >= CHW) return;
  int c = idx / HW;
  const float thv = th[c];
  size_t base = (size_t)blockIdx.y * 64 * CHW + idx;
  const float* p = X + base;
  uint8_t* q = Sp + base;
  float v = 0.f, ss = 0.f;
  #pragma unroll
  for (int t = 0; t < 64; ++t) {
    const float* pt = p + (size_t)t * CHW;
    float xv = pt[0];
    for (int u = 1; u < nparts; ++u) xv += pt[(size_t)u * pstride];
    v += xv;
    float s = (v >= thv) ? 1.f : 0.f;
    v -= s * thv;
    q[(size_t)t * CHW] = (uint8_t)s;
    ss += s;
  }
  if ((HW & 63) == 0) {
    for (int off = 32; off >= 1; off >>= 1) ss += __shfl_down(ss, off);
    if ((threadIdx.x & 63) == 0) atomicAdd(&ssum[c], ss);
  } else {
    atomicAdd(&ssum[c], ss);
  }
}

// Fused 2x2 avg-pool + integrate-and-fire on uint8 spikes.
__global__ __launch_bounds__(256) void k_ifpool(const uint8_t* __restrict__ Sin,
                                                uint8_t* __restrict__ Sp,
                                                const float* __restrict__ th,
                                                float* __restrict__ ssum,
                                                float* __restrict__ Sout,
                                                int C, int H) {
  const int Ho = H >> 1, HWo = Ho * Ho;
  const int CHWo = C * HWo;
  int idx = blockIdx.x * 256 + threadIdx.x;
  if (idx >= CHWo) return;
  int c = idx / HWo;
  int rem = idx - c * HWo;
  int ho = rem / Ho, wo = rem - ho * Ho;
  const float thv = th[c];
  const size_t istep = (size_t)C * H * H;
  const size_t ib = ((size_t)(blockIdx.y * 64) * C + c) * (H * H) + (2 * ho) * H + 2 * wo;
  uint8_t* q = Sp + (size_t)blockIdx.y * 64 * CHWo + idx;
  float v = 0.f, ss = 0.f;
  #pragma unroll
  for (int t = 0; t < 64; ++t) {
    const uint8_t* pp = Sin + ib + (size_t)t * istep;
    float xv = 0.25f * ((float)pp[0] + (float)pp[1] + (float)pp[H] + (float)pp[H + 1]);
    v += xv;
    float s = (v >= thv) ? 1.f : 0.f;
    v -= s * thv;
    q[(size_t)t * CHWo] = (uint8_t)s;
    ss += s;
  }
  if (Sout && HWo == 1) Sout[blockIdx.y * C + c] = ss;
  if ((HWo & 63) == 0) {
    for (int off = 32; off >= 1; off >>= 1) ss += __shfl_down(ss, off);
    if ((threadIdx.x & 63) == 0) atomicAdd(&ssum[c], ss);
  } else {
    atomicAdd(&ssum[c], ss);
  }
}

// Fused 2x2 avg-pool + quantize on analog path (batch 4).
__global__ __launch_bounds__(256) void k_ttypool(const float* __restrict__ yin,
                                                 float* __restrict__ yout,
                                                 float* __restrict__ ysum,
                                                 int C, int H) {
  const int Ho = H >> 1, HWo = Ho * Ho;
  int idx = blockIdx.x * 256 + threadIdx.x;
  if (idx >= 4 * C * HWo) return;
  int rem = idx % (C * HWo);
  int c = rem / HWo;
  int r2 = rem - c * HWo;
  int ho = r2 / Ho, wo = r2 - ho * Ho;
  int img = idx / (C * HWo);
  size_t base = (((size_t)img * C + c) * H + 2 * ho) * H + 2 * wo;
  float xv = 0.25f * (yin[base] + yin[base + 1] + yin[base + H] + yin[base + H + 1]);
  float v = floorf(xv * 64.f) * 0.015625f;
  v = fminf(fmaxf(v, 0.f), 1.f);
  yout[idx] = v;
  if ((HWo & 63) == 0) {
    for (int off = 32; off >= 1; off >>= 1) v += __shfl_down(v, off);
    if ((threadIdx.x & 63) == 0) atomicAdd(&ysum[c], v);
  } else {
    atomicAdd(&ysum[c], v);
  }
}

// Analog quantize; sums nparts partial conv outputs (K-split) first.
__global__ __launch_bounds__(256) void k_tty(const float* __restrict__ y4,
                                             float* __restrict__ yout,
                                             float* __restrict__ ysum,
                                             int C, int HW,
                                             int nparts, int pstride) {
  int idx = blockIdx.x * 256 + threadIdx.x;
  if (idx >= 4 * C * HW) return;
  int rem = idx % (C * HW);
  int c = rem / HW;
  float xv = 0.f;
  for (int p = 0; p < nparts; ++p) xv += y4[idx + (size_t)p * pstride];
  float v = floorf(xv * 64.f) * 0.015625f;
  v = fminf(fmaxf(v, 0.f), 1.f);
  yout[idx] = v;
  if ((HW & 63) == 0) {
    for (int off = 32; off >= 1; off >>= 1) v += __shfl_down(v, off);
    if ((threadIdx.x & 63) == 0) atomicAdd(&ysum[c], v);
  } else {
    atomicAdd(&ysum[c], v);
  }
}

__global__ void k_thr(const float* __restrict__ thin,
                      const float* __restrict__ ssum,
                      const float* __restrict__ ysum,
                      float* __restrict__ dst, int C, float invmul) {
  int c = blockIdx.x * 256 + threadIdx.x;
  if (c >= C) return;
  float diff = (ysum[c] * 64.f - ssum[c]) * invmul;
  dst[c] = thin[c] - 0.1f * diff;
}

__global__ void k_cls(const float* __restrict__ S, const float* __restrict__ wc,
                      const float* __restrict__ bcp, float* __restrict__ out) {
  int idx = blockIdx.x * 256 + threadIdx.x;
  if (idx >= 400) return;
  int n = idx / 100, o = idx - (idx / 100) * 100;
  const float* sp = S + n * 1024;
  const float* wp = wc + o * 1024;
  float acc = 0.f;
  for (int c = 0; c < 1024; ++c) acc += wp[c] * sp[c];
  out[idx] = acc * 0.015625f + bcp[o];
}

extern "C" void kernel_launch(void* const* d_in, const int* in_sizes, int n_in,
                              void* d_out_v, int out_size, void* d_ws, size_t ws_size,
                              hipStream_t stream) {
  const float *Ws[7], *Bs[7], *Wa[7], *Ba[7];
  for (int i = 0; i < 7; ++i) {
    Ws[i] = (const float*)d_in[i * 4 + 0];
    Bs[i] = (const float*)d_in[i * 4 + 1];
    Wa[i] = (const float*)d_in[i * 4 + 2];
    Ba[i] = (const float*)d_in[i * 4 + 3];
  }
  const float* wc = (const float*)d_in[28];
  const float* bc = (const float*)d_in[29];
  const float* x  = (const float*)d_in[30];
  const float* TH[7];
  for (int i = 0; i < 7; ++i) TH[i] = (const float*)d_in[31 + i];
  const float* P[4];
  for (int i = 0; i < 4; ++i) P[i] = (const float*)d_in[38 + i];
  float* out = (float*)d_out_v;

  // ---- workspace (107.7 MB) ----
  float* w = (float*)d_ws;
  const size_t RF = 8536064;      // [WT | CF0] region, per-layer split
  float* Rb = w;
  size_t off = RF;
  float* xbar = w + off; off += 12288;    // packed u32 hi/lo
  float* yA   = w + off; off += 524288;
  float* yB   = w + off; off += 524288;
  float* y4   = w + off; off += 524288;
  float* S    = w + off; off += 4096;
  float* sums = w + off; off += 11 * 2048;
  uint8_t* SA = (uint8_t*)(w + off);
  uint8_t* SB = SA + 33554432;
  size_t total_bytes = off * sizeof(float) + (size_t)2 * 33554432;
  if (ws_size < total_bytes) return;
  unsigned short* WT = (unsigned short*)Rb;
  unsigned* XT2 = (unsigned*)SB;          // aliases SB (dead until L2 output)
  unsigned* xbar2 = (unsigned*)xbar;

  hipMemsetAsync(sums, 0, 11 * 2048 * sizeof(float), stream);
  k_tpack<<<3072, 256, 0, stream>>>(x, XT2);
  k_xbar_pack<<<48, 256, 0, stream>>>(x, xbar2);

  int stage = 0;

  // ---- L1 (MFMA im2col) ----
  {
    float* CF = Rb + 4096;                 // WT1 = 16 KB
    float* ss = sums; float* ys = ss + 1024;
    k_wxform1<<<2, 256, 0, stream>>>(Ws[0], WT);
    for (int c = 0; c < 4; ++c) {
      k_l1<<<dim3(2, 256), 256, 0, stream>>>(XT2 + (size_t)c * 64 * 3072, WT, Bs[0], CF, 64);
      k_if<<<dim3(512, 1), 256, 0, stream>>>(CF, SA + (size_t)c * 64 * 131072,
                                             TH[0], ss, 128, 1024, 1, 0);
    }
    k_wxform1<<<2, 256, 0, stream>>>(Wa[0], WT);
    k_l1<<<dim3(2, 16), 256, 0, stream>>>(xbar2, WT, Ba[0], y4, 4);
    k_tty<<<2048, 256, 0, stream>>>(y4, yA, ys, 128, 1024, 1, 0);
    k_thr<<<1, 256, 0, stream>>>(TH[0], ss, ys, out + 400, 128, 1.0f / (4.f * 1024.f * 64.f));
    ++stage;
  }

  // ---- generic pad=1 MFMA layer ----
  // Spike conv: G=8 co-split (MT=128 px), optional kz (partials at CF1).
  // Analog conv (batch 4): G=4 co-split (MT=64), aTRI/atpi geometry, akz in y4.
  auto mfma_layer = [&](const uint8_t* inS, uint8_t* outS, const float* inY, float* outY,
                        int li, int Ci, int Co, int W, int TRI, int tpi, int NIMG,
                        int chunkImgs, int kzn, float* CF1,
                        int aTRI, int atpi, int akz,
                        const float* thin, int outoff) {
    const int HW = W * W;
    const int CHWo = Co * HW;
    const int nch = Ci >> 5;
    float* ss = sums + stage * 2048; float* ys = ss + 1024;
    float* CF = Rb + (size_t)Co * Ci * 9;
    size_t osplit = (kzn == 2) ? (size_t)(CF1 - CF) : 0;
    int xgrid = ((Co / 64) * nch * 9 * 4 * 64 + 255) / 256;
    k_wxform<<<xgrid, 256, 0, stream>>>(Ws[li], WT, Ci, Co);
    int nchk = 256 / chunkImgs;
    int mt = (chunkImgs / NIMG) * tpi;
    for (int c = 0; c < nchk; ++c) {
      k_cmfma<uint8_t, false, 8, 1><<<dim3(Co / 64, mt, kzn), 256, 0, stream>>>(
          inS + (size_t)c * chunkImgs * Ci * HW, WT, Bs[li], CF,
          Ci, Co, W, TRI, tpi, NIMG, chunkImgs, nch / kzn, osplit);
      k_if<<<dim3((CHWo + 255) / 256, chunkImgs / 64), 256, 0, stream>>>(
          CF, outS + (size_t)c * chunkImgs * CHWo, thin, ss, Co, HW, kzn, osplit);
    }
    k_wxform<<<xgrid, 256, 0, stream>>>(Wa[li], WT, Ci, Co);
    int aosplit = 4 * CHWo;
    k_cmfma<float, false, 4, 1><<<dim3(Co / 64, 4 * atpi, akz), 256, 0, stream>>>(
        inY, WT, Ba[li], y4, Ci, Co, W, aTRI, atpi, 1, 4, nch / akz, (size_t)aosplit);
    k_tty<<<(4 * CHWo + 255) / 256, 256, 0, stream>>>(y4, outY, ys, Co, HW, akz, aosplit);
    k_thr<<<(Co + 255) / 256, 256, 0, stream>>>(thin, ss, ys, out + outoff, Co,
                                                1.0f / (4.f * HW * 64.f));
    ++stage;
  };

  auto pool_stage = [&](const uint8_t* inS, uint8_t* outS, const float* inY, float* outY,
                        int C, int H, const float* pthr, int outoff, float* Sout) {
    const int Ho = H / 2, HWo = Ho * Ho;
    const int CHWo = C * HWo;
    float* ss = sums + stage * 2048; float* ys = ss + 1024;
    k_ifpool<<<dim3((CHWo + 255) / 256, 4), 256, 0, stream>>>(inS, outS, pthr, ss, Sout, C, H);
    k_ttypool<<<(4 * CHWo + 255) / 256, 256, 0, stream>>>(inY, outY, ys, C, H);
    k_thr<<<(C + 255) / 256, 256, 0, stream>>>(pthr, ss, ys, out + outoff, C,
                                               1.0f / (4.f * HWo * 64.f));
    ++stage;
  };

  // L2: spike TRI=4,tpi=8 -> grid(2,512,1); analog aTRI=2,atpi=16, akz=1
  mfma_layer(SA, SB, yA, yB, 1, 128, 128, 32, 4, 8, 1, 64, 1, nullptr,
             2, 16, 1, TH[1], 528);
  // P1
  pool_stage(SB, SA, yB, yA, 128, 32, P[0], 3216, nullptr);
  // L3: spike TRI=8,tpi=2, kz=2 (partial SB tail) -> grid(4,128,2)
  mfma_layer(SA, SB, yA, yB, 2, 128, 256, 16, 8, 2, 1, 64, 2,
             (float*)(SB + 16777216), 4, 4, 2, TH[2], 656);
  // L4
  mfma_layer(SB, SA, yB, yA, 3, 256, 256, 16, 8, 2, 1, 64, 2,
             (float*)(SA + 16777216), 4, 4, 2, TH[3], 912);
  // P2
  pool_stage(SA, SB, yA, yB, 256, 16, P[1], 3344, nullptr);
  // L5: spike NIMG=2,TRI=8,tpi=1, kz=2 -> grid(8,64,2)
  mfma_layer(SB, SA, yB, yA, 4, 256, 512, 8, 8, 1, 2, 128, 2,
             (float*)(SA + 8388608), 8, 1, 4, TH[4], 1168);
  // L6
  mfma_layer(SA, SB, yA, yB, 5, 512, 512, 8, 8, 1, 2, 128, 2,
             (float*)(SB + 8388608), 8, 1, 4, TH[5], 1680);
  // P3
  pool_stage(SB, SA, yB, yA, 512, 8, P[2], 3600, nullptr);
  // L7 (pad=0): spike kz=4, partials in SA tail; analog akz=8 in y4
  {
    float* ss = sums + stage * 2048; float* ys = ss + 1024;
    float* CF = (float*)(SA + 4194304);         // 4 partials x 4.2 MB
    const size_t osplit = 1048576;              // 256*1024*4 elems
    int xgrid = (16 * 16 * 9 * 4 * 64 + 255) / 256;
    k_wxform<<<xgrid, 256, 0, stream>>>(Ws[6], WT, 512, 1024);
    k_cmfma<uint8_t, true, 8, 1><<<dim3(16, 8, 4), 256, 0, stream>>>(
        SA, WT, Bs[6], CF, 512, 1024, 4, 0, 1, 0, 256, 4, osplit);
    k_if<<<dim3(16, 4), 256, 0, stream>>>(CF, SB, TH[6], ss, 1024, 4, 4, osplit);
    k_wxform<<<xgrid, 256, 0, stream>>>(Wa[6], WT, 512, 1024);
    k_cmfma<float, true, 4, 1><<<dim3(16, 1, 8), 256, 0, stream>>>(
        yA, WT, Ba[6], y4, 512, 1024, 4, 0, 1, 0, 4, 2, 16384);
    k_tty<<<64, 256, 0, stream>>>(y4, yB, ys, 1024, 4, 8, 16384);
    k_thr<<<4, 256, 0, stream>>>(TH[6], ss, ys, out + 2192, 1024, 1.0f / 1024.f);
    ++stage;
  }
  // P4: fused pool+IF also writes S directly
  pool_stage(SB, SA, yB, yA, 1024, 2, P[3], 4112, S);
  // classifier
  k_cls<<<2, 256, 0, stream>>>(S, wc, bc, out);
}

// Round 14
// 1800.388 us; speedup vs baseline: 1.4218x; 1.1105x over previous
//
#include <hip/hip_runtime.h>
#include <cstdint>
#include <cstddef>

// ---------------------------------------------------------------------------
// SNN "CatNet" forward, MFMA v9.
// Spiking tensors: uint8 [(n*64+t), C, H, W] (exact 0/1).
// All convs run as bf16 MFMA implicit-GEMM with hi/lo split weights.
// v9: generalized wave shape <GW px-frags, NPG px-groups> with CW=NPG
// co-frags/wave. Spike convs use (GW=8, NPG=2): wave = 32co x 128px,
// block 64co x 256px -> A-feed and B-feed both ~halved per unit of work
// vs round-13 co-split. Analog (GW=4,NPG=1) and L7 (GW=8,NPG=1) unchanged.
// ---------------------------------------------------------------------------

typedef short short8 __attribute__((ext_vector_type(8)));   // 8 bf16
typedef float floatx4 __attribute__((ext_vector_type(4)));

__device__ __forceinline__ unsigned short f2bf_rne(float f) {
  unsigned u = __float_as_uint(f);
  return (unsigned short)((u + 0x7FFFu + ((u >> 16) & 1u)) >> 16);
}
__device__ __forceinline__ float bf2f(unsigned short h) {
  return __uint_as_float((unsigned)h << 16);
}

// ---------------------------------------------------------------------------
// Weight pre-transform (3x3 layers): W f32 [Co][Ci][3][3] -> bf16 hi/lo frags.
// frag(cot,ch,tap,cg,h) at shorts: (cot*nch+ch)*36864 + tap*4096 + cg*1024
//                                  + h*512 + lane*8      (ch in 32-ci units)
// ---------------------------------------------------------------------------
__global__ __launch_bounds__(256) void k_wxform(const float* __restrict__ Wsrc,
                                                unsigned short* __restrict__ wt,
                                                int Ci, int Co) {
  const int nch = Ci >> 5;
  const int total = (Co >> 6) * nch * 9 * 4 * 64;
  int idx = blockIdx.x * 256 + threadIdx.x;
  if (idx >= total) return;
  int lane = idx & 63;
  int t2 = idx >> 6;
  int cg = t2 & 3;
  int t3 = t2 >> 2;
  int tap = t3 % 9;
  int t4 = t3 / 9;
  int ch = t4 % nch;
  int cot = t4 / nch;
  int co = cot * 64 + cg * 16 + (lane & 15);
  int cib = ch * 32 + (lane >> 4) * 8;
  short8 vh, vl;
  #pragma unroll
  for (int j = 0; j < 8; ++j) {
    float wv = Wsrc[((size_t)co * Ci + cib + j) * 9 + tap];
    unsigned short h = f2bf_rne(wv);
    vh[j] = (short)h;
    vl[j] = (short)f2bf_rne(wv - bf2f(h));
  }
  size_t base = ((((size_t)cot * nch + ch) * 9 + tap) * 4 + cg) * 1024 + (size_t)lane * 8;
  *(short8*)&wt[base] = vh;
  *(short8*)&wt[base + 512] = vl;
}

// L1 weight transform: W f32 [128][3][3][3] -> K=32 frags, k = tap*3+ci.
__global__ __launch_bounds__(256) void k_wxform1(const float* __restrict__ Wsrc,
                                                 unsigned short* __restrict__ wt) {
  int idx = blockIdx.x * 256 + threadIdx.x;   // 512 total
  if (idx >= 512) return;
  int lane = idx & 63, cg = (idx >> 6) & 3, cot = idx >> 8;
  int co = cot * 64 + cg * 16 + (lane & 15);
  short8 vh, vl;
  #pragma unroll
  for (int e = 0; e < 8; ++e) {
    int k = (lane >> 4) * 8 + e;
    float wv = 0.f;
    if (k < 27) { int tap = k / 3, ci = k - 3 * tap; wv = Wsrc[(co * 3 + ci) * 9 + tap]; }
    unsigned short h = f2bf_rne(wv);
    vh[e] = (short)h;
    vl[e] = (short)f2bf_rne(wv - bf2f(h));
  }
  size_t base = (size_t)cot * 4096 + cg * 1024 + (size_t)lane * 8;
  *(short8*)&wt[base] = vh;
  *(short8*)&wt[base + 512] = vl;
}

// Transpose+pack x: [n][c][hw][t] f32 -> XT2[(n*64+t)][c][hw] u32 = hi|lo<<16
__global__ __launch_bounds__(256) void k_tpack(const float* __restrict__ x,
                                               unsigned* __restrict__ XT2) {
  int idx = blockIdx.x * 256 + threadIdx.x;   // 786432
  int b = idx / 3072;
  int rem = idx - b * 3072;
  int t = b & 63, n = b >> 6;
  float f = x[((size_t)(n * 3072 + rem)) * 64 + t];
  unsigned short h = f2bf_rne(f);
  unsigned short l = f2bf_rne(f - bf2f(h));
  XT2[idx] = (unsigned)h | ((unsigned)l << 16);
}

__global__ __launch_bounds__(256) void k_xbar_pack(const float* __restrict__ x,
                                                   unsigned* __restrict__ xb) {
  int idx = blockIdx.x * 256 + threadIdx.x;   // 12288
  if (idx >= 12288) return;
  const float* p = x + (size_t)idx * 64;
  float s = 0.f;
  #pragma unroll
  for (int t = 0; t < 64; ++t) s += p[t];
  s *= 0.015625f;
  unsigned short h = f2bf_rne(s);
  unsigned short l = f2bf_rne(s - bf2f(h));
  xb[idx] = (unsigned)h | ((unsigned)l << 16);
}

// ---------------------------------------------------------------------------
// MFMA conv, generic 3x3. PAD0=false: pad=1 square W; PAD0=true: L7 (4x4->2x2).
// 4 waves arranged NCG=4/NPG co-groups x NPG px-groups; wave wv: cog=wv/NPG,
// pxg=wv%NPG. Wave computes CW=NPG co-frags x GW px-frags. Block tile =
// 64co x (16*GW*NPG)px. A (CW*2 hi/lo frags/step) from global, disjoint per
// co-group; B from LDS (stride-40-short rows).
// grid.z = K-split: 32-ci chunks [z*nchPer, (z+1)*nchPer), out += z*osplit,
// bias added only by z==0.
// ---------------------------------------------------------------------------
template <typename T, bool PAD0, int GW, int NPG>
__global__ __launch_bounds__(256, 1) void k_cmfma(
    const T* __restrict__ in, const unsigned short* __restrict__ wt,
    const float* __restrict__ bs, float* __restrict__ out,
    int Ci, int Co, int W, int TRI, int tpi, int NIMG, int nImgValid,
    int nchPer, size_t osplit) {
  constexpr int CW = NPG;
  constexpr int MT = 16 * GW * NPG;          // block m-tile
  constexpr int PPXMAX = PAD0 ? (MT / 4) * 16 : 400;
  constexpr int STR = 40;                    // LDS row stride (shorts)
  __shared__ unsigned short sIn[PPXMAX * STR];
  const int tid = threadIdx.x;
  const int lane = tid & 63;
  const int wv = tid >> 6;
  const int cog = wv / NPG;
  const int pxg = wv % NPG;
  const int cot = blockIdx.x;
  const int mtile = blockIdx.y;
  const int kz = blockIdx.z;
  const int nch = Ci >> 5;
  const int nchA = kz * nchPer, nchB = nchA + nchPer;
  out += (size_t)kz * osplit;
  const int addBias = (kz == 0);

  int img_first, r0 = 0, PPR, PPX;
  if constexpr (PAD0) {
    img_first = mtile * (MT / 4);
    PPR = 16; PPX = (MT / 4) * 16;
  } else {
    img_first = (mtile / tpi) * NIMG;
    r0 = (mtile % tpi) * TRI;
    PPR = (TRI + 2) * (W + 2);
    PPX = NIMG * PPR;
  }
  const int TRW = TRI * W;

  // output / B-fragment mapping: m = pxg*GW*16 + g*16 + (lane&15)
  int p0[GW], mimg[GW], mopx[GW];
  #pragma unroll
  for (int g = 0; g < GW; ++g) {
    int m = pxg * (GW * 16) + g * 16 + (lane & 15);
    int limg;
    if constexpr (PAD0) {
      limg = m >> 2;
      int o = m & 3;
      p0[g] = limg * 16 + (o >> 1) * 4 + (o & 1);
      mopx[g] = (o >> 1) * 2 + (o & 1);
    } else {
      limg = m / TRW;
      int rm = m - limg * TRW;
      int r = rm / W, c = rm - r * W;
      p0[g] = limg * PPR + r * (W + 2) + c;
      mopx[g] = (r0 + r) * W + c;
    }
    mimg[g] = img_first + limg;
  }
  int psh[9];
  #pragma unroll
  for (int t = 0; t < 9; ++t) {
    int dh = t / 3, dw = t - dh * 3;
    psh[t] = PAD0 ? (dh * 4 + dw) : (dh * (W + 2) + dw);
  }

  // staging precompute (<=2 px per thread), idiv only here
  const int HWin = PAD0 ? 16 : W * W;
  int sgofs[2]; bool svalid[2];
  #pragma unroll
  for (int i = 0; i < 2; ++i) {
    int p = tid + i * 256;
    svalid[i] = false; sgofs[i] = 0;
    if (p < PPX) {
      int limg, gpx;
      if constexpr (PAD0) {
        limg = p >> 4; gpx = p & 15;
      } else {
        limg = p / PPR;
        int rem = p - limg * PPR;
        int pr = rem / (W + 2), pc = rem - pr * (W + 2);
        int gr = r0 + pr - 1, gc = pc - 1;
        gpx = (gr >= 0 && gr < W && gc >= 0 && gc < W) ? gr * W + gc : -1;
      }
      int img = img_first + limg;
      if (gpx >= 0 && img < nImgValid) {
        svalid[i] = true;
        sgofs[i] = img * Ci * HWin + gpx;
      }
    }
  }
  const int kb = (lane >> 4) * 8;

  floatx4 acc[CW][GW];
  floatx4 zero = {0.f, 0.f, 0.f, 0.f};
  #pragma unroll
  for (int cw = 0; cw < CW; ++cw)
    #pragma unroll
    for (int g = 0; g < GW; ++g) acc[cw][g] = zero;

  for (int ch = nchA; ch < nchB; ++ch) {
    const int ci0 = ch * 32;
    // ---- stage input patch [px][32 ci] as bf16, packed b128 writes ----
    #pragma unroll
    for (int i = 0; i < 2; ++i) {
      int p = tid + i * 256;
      if (p < PPX) {
        unsigned short* dst = &sIn[p * STR];
        if (svalid[i]) {
          const T* sp = in + sgofs[i] + (size_t)ci0 * HWin;
          #pragma unroll
          for (int j = 0; j < 4; ++j) {
            short8 v;
            #pragma unroll
            for (int e = 0; e < 8; ++e) {
              if constexpr (sizeof(T) == 1)
                v[e] = sp[(size_t)(j * 8 + e) * HWin] ? (short)0x3F80 : (short)0;
              else
                v[e] = (short)f2bf_rne(((const float*)sp)[(size_t)(j * 8 + e) * HWin]);
            }
            *(short8*)&dst[j * 8] = v;
          }
        } else {
          short8 z = {};
          #pragma unroll
          for (int j = 0; j < 4; ++j) *(short8*)&dst[j * 8] = z;
        }
      }
    }
    __syncthreads();
    // ---- 9 taps; A = this wave's CW cg-slices (hi/lo), double-buffered ----
    const unsigned short* wbase = wt + ((size_t)(cot * nch + ch)) * 36864
                                  + (size_t)(cog * CW) * 1024 + (size_t)lane * 8;
    short8 A[2][CW * 2];
    #pragma unroll
    for (int cw = 0; cw < CW; ++cw) {
      A[0][cw * 2 + 0] = *(const short8*)(wbase + cw * 1024);
      A[0][cw * 2 + 1] = *(const short8*)(wbase + cw * 1024 + 512);
    }
    #pragma unroll
    for (int t = 0; t < 9; ++t) {
      const int cur = t & 1;
      if (t < 8) {
        const unsigned short* wp = wbase + (size_t)(t + 1) * 4096;
        #pragma unroll
        for (int cw = 0; cw < CW; ++cw) {
          A[cur ^ 1][cw * 2 + 0] = *(const short8*)(wp + cw * 1024);
          A[cur ^ 1][cw * 2 + 1] = *(const short8*)(wp + cw * 1024 + 512);
        }
      }
      short8 b[GW];
      #pragma unroll
      for (int g = 0; g < GW; ++g)
        b[g] = *(const short8*)&sIn[(p0[g] + psh[t]) * STR + kb];
      #pragma unroll
      for (int cw = 0; cw < CW; ++cw) {
        #pragma unroll
        for (int g = 0; g < GW; ++g) {
          acc[cw][g] = __builtin_amdgcn_mfma_f32_16x16x32_bf16(A[cur][cw * 2 + 0], b[g], acc[cw][g], 0, 0, 0);
          acc[cw][g] = __builtin_amdgcn_mfma_f32_16x16x32_bf16(A[cur][cw * 2 + 1], b[g], acc[cw][g], 0, 0, 0);
        }
      }
    }
    __syncthreads();
  }
  // ---- epilogue: co = cot*64 + (cog*CW+cw)*16 + (lane>>4)*4 + i2 ----
  const int HWout = PAD0 ? 4 : W * W;
  #pragma unroll
  for (int g = 0; g < GW; ++g) {
    if (mimg[g] >= nImgValid) continue;
    #pragma unroll
    for (int cw = 0; cw < CW; ++cw) {
      #pragma unroll
      for (int i2 = 0; i2 < 4; ++i2) {
        int co = cot * 64 + (cog * CW + cw) * 16 + (lane >> 4) * 4 + i2;
        float bv = addBias ? bs[co] : 0.f;
        out[((size_t)mimg[g] * Co + co) * HWout + mopx[g]] = acc[cw][g][i2] + bv;
      }
    }
  }
}

// ---------------------------------------------------------------------------
// L1 MFMA conv: K=32 im2col (k=tap*3+ci), input packed hi/lo u32.
// ---------------------------------------------------------------------------
__global__ __launch_bounds__(256, 1) void k_l1(const unsigned* __restrict__ xin,
                                               const unsigned short* __restrict__ wt,
                                               const float* __restrict__ bs,
                                               float* __restrict__ out,
                                               int nImgValid) {
  __shared__ unsigned short sIn[256 * 72];   // [m][hi(32) | lo(32)], stride 72
  const int tid = threadIdx.x, lane = tid & 63, wv = tid >> 6;
  const int cot = blockIdx.x, mtile = blockIdx.y;
  const int img = mtile >> 2;
  const int r0 = (mtile & 3) * 8;
  {
    int m = tid;
    int r = r0 + (m >> 5), c = m & 31;
    const unsigned* ip = xin + (size_t)img * 3072;
    unsigned v[9][3];
    bool iv = (img < nImgValid);
    #pragma unroll
    for (int dh = 0; dh < 3; ++dh) {
      #pragma unroll
      for (int dw = 0; dw < 3; ++dw) {
        int rr = r + dh - 1, cc = c + dw - 1;
        bool ok = iv && rr >= 0 && rr < 32 && cc >= 0 && cc < 32;
        #pragma unroll
        for (int ci = 0; ci < 3; ++ci)
          v[dh * 3 + dw][ci] = ok ? ip[ci * 1024 + rr * 32 + cc] : 0u;
      }
    }
    #pragma unroll
    for (int j = 0; j < 4; ++j) {
      short8 vh, vl;
      #pragma unroll
      for (int e = 0; e < 8; ++e) {
        int k = j * 8 + e;
        unsigned u = (k < 27) ? v[k / 3][k - 3 * (k / 3)] : 0u;
        vh[e] = (short)(u & 0xFFFFu);
        vl[e] = (short)(u >> 16);
      }
      *(short8*)&sIn[m * 72 + j * 8] = vh;
      *(short8*)&sIn[m * 72 + 32 + j * 8] = vl;
    }
  }
  __syncthreads();
  const int kb = (lane >> 4) * 8;
  const unsigned short* wb = wt + (size_t)cot * 4096 + (size_t)lane * 8;
  short8 Af[8];
  #pragma unroll
  for (int f = 0; f < 8; ++f)
    Af[f] = *(const short8*)(wb + (f >> 1) * 1024 + (f & 1) * 512);
  floatx4 acc[4][4];
  floatx4 zero = {0.f, 0.f, 0.f, 0.f};
  #pragma unroll
  for (int cg = 0; cg < 4; ++cg)
    #pragma unroll
    for (int g = 0; g < 4; ++g) acc[cg][g] = zero;
  short8 bh[4], bl[4];
  #pragma unroll
  for (int g = 0; g < 4; ++g) {
    int m = wv * 64 + g * 16 + (lane & 15);
    bh[g] = *(const short8*)&sIn[m * 72 + kb];
    bl[g] = *(const short8*)&sIn[m * 72 + 32 + kb];
  }
  #pragma unroll
  for (int cg = 0; cg < 4; ++cg) {
    #pragma unroll
    for (int g = 0; g < 4; ++g) {
      acc[cg][g] = __builtin_amdgcn_mfma_f32_16x16x32_bf16(Af[cg * 2 + 0], bh[g], acc[cg][g], 0, 0, 0);
      acc[cg][g] = __builtin_amdgcn_mfma_f32_16x16x32_bf16(Af[cg * 2 + 0], bl[g], acc[cg][g], 0, 0, 0);
      acc[cg][g] = __builtin_amdgcn_mfma_f32_16x16x32_bf16(Af[cg * 2 + 1], bh[g], acc[cg][g], 0, 0, 0);
    }
  }
  if (img >= nImgValid) return;
  #pragma unroll
  for (int g = 0; g < 4; ++g) {
    int mbase = wv * 64 + g * 16 + (lane & 15);
    int px = (r0 + (mbase >> 5)) * 32 + (mbase & 31);
    #pragma unroll
    for (int cg = 0; cg < 4; ++cg) {
      #pragma unroll
      for (int i2 = 0; i2 < 4; ++i2) {
        int co = cot * 64 + cg * 16 + (lane >> 4) * 4 + i2;
        out[((size_t)img * 128 + co) * 1024 + px] = acc[cg][g][i2] + bs[co];
      }
    }
  }
}

// ---------------------------------------------------------------------------
// Integrate-and-fire; blockIdx.y = 64-t group. Sums nparts partials.
__global__ __launch_bounds__(256) void k_if(const float* __restrict__ X,
                                            uint8_t* __restrict__ Sp,
                                            const float* __restrict__ th,
                                            float* __restrict__ ssum,
                                            int C, int HW,
                                            int nparts, size_t pstride) {
  const int CHW = C * HW;
  int idx = blockIdx.x * 256 + threadIdx.x;
  if (idx >= CHW) return;
  int c = idx / HW;
  const float thv = th[c];
  size_t base = (size_t)blockIdx.y * 64 * CHW + idx;
  const float* p = X + base;
  uint8_t* q = Sp + base;
  float v = 0.f, ss = 0.f;
  #pragma unroll
  for (int t = 0; t < 64; ++t) {
    const float* pt = p + (size_t)t * CHW;
    float xv = pt[0];
    for (int u = 1; u < nparts; ++u) xv += pt[(size_t)u * pstride];
    v += xv;
    float s = (v >= thv) ? 1.f : 0.f;
    v -= s * thv;
    q[(size_t)t * CHW] = (uint8_t)s;
    ss += s;
  }
  if ((HW & 63) == 0) {
    for (int off = 32; off >= 1; off >>= 1) ss += __shfl_down(ss, off);
    if ((threadIdx.x & 63) == 0) atomicAdd(&ssum[c], ss);
  } else {
    atomicAdd(&ssum[c], ss);
  }
}

// Fused 2x2 avg-pool + integrate-and-fire on uint8 spikes.
__global__ __launch_bounds__(256) void k_ifpool(const uint8_t* __restrict__ Sin,
                                                uint8_t* __restrict__ Sp,
                                                const float* __restrict__ th,
                                                float* __restrict__ ssum,
                                                float* __restrict__ Sout,
                                                int C, int H) {
  const int Ho = H >> 1, HWo = Ho * Ho;
  const int CHWo = C * HWo;
  int idx = blockIdx.x * 256 + threadIdx.x;
  if (idx >= CHWo) return;
  int c = idx / HWo;
  int rem = idx - c * HWo;
  int ho = rem / Ho, wo = rem - ho * Ho;
  const float thv = th[c];
  const size_t istep = (size_t)C * H * H;
  const size_t ib = ((size_t)(blockIdx.y * 64) * C + c) * (H * H) + (2 * ho) * H + 2 * wo;
  uint8_t* q = Sp + (size_t)blockIdx.y * 64 * CHWo + idx;
  float v = 0.f, ss = 0.f;
  #pragma unroll
  for (int t = 0; t < 64; ++t) {
    const uint8_t* pp = Sin + ib + (size_t)t * istep;
    float xv = 0.25f * ((float)pp[0] + (float)pp[1] + (float)pp[H] + (float)pp[H + 1]);
    v += xv;
    float s = (v >= thv) ? 1.f : 0.f;
    v -= s * thv;
    q[(size_t)t * CHWo] = (uint8_t)s;
    ss += s;
  }
  if (Sout && HWo == 1) Sout[blockIdx.y * C + c] = ss;
  if ((HWo & 63) == 0) {
    for (int off = 32; off >= 1; off >>= 1) ss += __shfl_down(ss, off);
    if ((threadIdx.x & 63) == 0) atomicAdd(&ssum[c], ss);
  } else {
    atomicAdd(&ssum[c], ss);
  }
}

// Fused 2x2 avg-pool + quantize on analog path (batch 4).
__global__ __launch_bounds__(256) void k_ttypool(const float* __restrict__ yin,
                                                 float* __restrict__ yout,
                                                 float* __restrict__ ysum,
                                                 int C, int H) {
  const int Ho = H >> 1, HWo = Ho * Ho;
  int idx = blockIdx.x * 256 + threadIdx.x;
  if (idx >= 4 * C * HWo) return;
  int rem = idx % (C * HWo);
  int c = rem / HWo;
  int r2 = rem - c * HWo;
  int ho = r2 / Ho, wo = r2 - ho * Ho;
  int img = idx / (C * HWo);
  size_t base = (((size_t)img * C + c) * H + 2 * ho) * H + 2 * wo;
  float xv = 0.25f * (yin[base] + yin[base + 1] + yin[base + H] + yin[base + H + 1]);
  float v = floorf(xv * 64.f) * 0.015625f;
  v = fminf(fmaxf(v, 0.f), 1.f);
  yout[idx] = v;
  if ((HWo & 63) == 0) {
    for (int off = 32; off >= 1; off >>= 1) v += __shfl_down(v, off);
    if ((threadIdx.x & 63) == 0) atomicAdd(&ysum[c], v);
  } else {
    atomicAdd(&ysum[c], v);
  }
}

// Analog quantize; sums nparts partial conv outputs (K-split) first.
__global__ __launch_bounds__(256) void k_tty(const float* __restrict__ y4,
                                             float* __restrict__ yout,
                                             float* __restrict__ ysum,
                                             int C, int HW,
                                             int nparts, int pstride) {
  int idx = blockIdx.x * 256 + threadIdx.x;
  if (idx >= 4 * C * HW) return;
  int rem = idx % (C * HW);
  int c = rem / HW;
  float xv = 0.f;
  for (int p = 0; p < nparts; ++p) xv += y4[idx + (size_t)p * pstride];
  float v = floorf(xv * 64.f) * 0.015625f;
  v = fminf(fmaxf(v, 0.f), 1.f);
  yout[idx] = v;
  if ((HW & 63) == 0) {
    for (int off = 32; off >= 1; off >>= 1) v += __shfl_down(v, off);
    if ((threadIdx.x & 63) == 0) atomicAdd(&ysum[c], v);
  } else {
    atomicAdd(&ysum[c], v);
  }
}

__global__ void k_thr(const float* __restrict__ thin,
                      const float* __restrict__ ssum,
                      const float* __restrict__ ysum,
                      float* __restrict__ dst, int C, float invmul) {
  int c = blockIdx.x * 256 + threadIdx.x;
  if (c >= C) return;
  float diff = (ysum[c] * 64.f - ssum[c]) * invmul;
  dst[c] = thin[c] - 0.1f * diff;
}

__global__ void k_cls(const float* __restrict__ S, const float* __restrict__ wc,
                      const float* __restrict__ bcp, float* __restrict__ out) {
  int idx = blockIdx.x * 256 + threadIdx.x;
  if (idx >= 400) return;
  int n = idx / 100, o = idx - (idx / 100) * 100;
  const float* sp = S + n * 1024;
  const float* wp = wc + o * 1024;
  float acc = 0.f;
  for (int c = 0; c < 1024; ++c) acc += wp[c] * sp[c];
  out[idx] = acc * 0.015625f + bcp[o];
}

extern "C" void kernel_launch(void* const* d_in, const int* in_sizes, int n_in,
                              void* d_out_v, int out_size, void* d_ws, size_t ws_size,
                              hipStream_t stream) {
  const float *Ws[7], *Bs[7], *Wa[7], *Ba[7];
  for (int i = 0; i < 7; ++i) {
    Ws[i] = (const float*)d_in[i * 4 + 0];
    Bs[i] = (const float*)d_in[i * 4 + 1];
    Wa[i] = (const float*)d_in[i * 4 + 2];
    Ba[i] = (const float*)d_in[i * 4 + 3];
  }
  const float* wc = (const float*)d_in[28];
  const float* bc = (const float*)d_in[29];
  const float* x  = (const float*)d_in[30];
  const float* TH[7];
  for (int i = 0; i < 7; ++i) TH[i] = (const float*)d_in[31 + i];
  const float* P[4];
  for (int i = 0; i < 4; ++i) P[i] = (const float*)d_in[38 + i];
  float* out = (float*)d_out_v;

  // ---- workspace (107.7 MB) ----
  float* w = (float*)d_ws;
  const size_t RF = 8536064;      // [WT | CF0] region, per-layer split
  float* Rb = w;
  size_t off = RF;
  float* xbar = w + off; off += 12288;    // packed u32 hi/lo
  float* yA   = w + off; off += 524288;
  float* yB   = w + off; off += 524288;
  float* y4   = w + off; off += 524288;
  float* S    = w + off; off += 4096;
  float* sums = w + off; off += 11 * 2048;
  uint8_t* SA = (uint8_t*)(w + off);
  uint8_t* SB = SA + 33554432;
  size_t total_bytes = off * sizeof(float) + (size_t)2 * 33554432;
  if (ws_size < total_bytes) return;
  unsigned short* WT = (unsigned short*)Rb;
  unsigned* XT2 = (unsigned*)SB;          // aliases SB (dead until L2 output)
  unsigned* xbar2 = (unsigned*)xbar;

  hipMemsetAsync(sums, 0, 11 * 2048 * sizeof(float), stream);
  k_tpack<<<3072, 256, 0, stream>>>(x, XT2);
  k_xbar_pack<<<48, 256, 0, stream>>>(x, xbar2);

  int stage = 0;

  // ---- L1 (MFMA im2col) ----
  {
    float* CF = Rb + 4096;                 // WT1 = 16 KB
    float* ss = sums; float* ys = ss + 1024;
    k_wxform1<<<2, 256, 0, stream>>>(Ws[0], WT);
    for (int c = 0; c < 4; ++c) {
      k_l1<<<dim3(2, 256), 256, 0, stream>>>(XT2 + (size_t)c * 64 * 3072, WT, Bs[0], CF, 64);
      k_if<<<dim3(512, 1), 256, 0, stream>>>(CF, SA + (size_t)c * 64 * 131072,
                                             TH[0], ss, 128, 1024, 1, 0);
    }
    k_wxform1<<<2, 256, 0, stream>>>(Wa[0], WT);
    k_l1<<<dim3(2, 16), 256, 0, stream>>>(xbar2, WT, Ba[0], y4, 4);
    k_tty<<<2048, 256, 0, stream>>>(y4, yA, ys, 128, 1024, 1, 0);
    k_thr<<<1, 256, 0, stream>>>(TH[0], ss, ys, out + 400, 128, 1.0f / (4.f * 1024.f * 64.f));
    ++stage;
  }

  // ---- generic pad=1 MFMA layer ----
  // Spike conv: <GW=8,NPG=2> (block 64co x 256px). Analog: <GW=4,NPG=1>.
  auto mfma_layer = [&](const uint8_t* inS, uint8_t* outS, const float* inY, float* outY,
                        int li, int Ci, int Co, int W, int TRI, int tpi, int NIMG,
                        int chunkImgs, int kzn, float* CF1,
                        int aTRI, int atpi, int akz,
                        const float* thin, int outoff) {
    const int HW = W * W;
    const int CHWo = Co * HW;
    const int nch = Ci >> 5;
    float* ss = sums + stage * 2048; float* ys = ss + 1024;
    float* CF = Rb + (size_t)Co * Ci * 9;
    size_t osplit = (kzn == 2) ? (size_t)(CF1 - CF) : 0;
    int xgrid = ((Co / 64) * nch * 9 * 4 * 64 + 255) / 256;
    k_wxform<<<xgrid, 256, 0, stream>>>(Ws[li], WT, Ci, Co);
    int nchk = 256 / chunkImgs;
    int mt = (chunkImgs / NIMG) * tpi;
    for (int c = 0; c < nchk; ++c) {
      k_cmfma<uint8_t, false, 8, 2><<<dim3(Co / 64, mt, kzn), 256, 0, stream>>>(
          inS + (size_t)c * chunkImgs * Ci * HW, WT, Bs[li], CF,
          Ci, Co, W, TRI, tpi, NIMG, chunkImgs, nch / kzn, osplit);
      k_if<<<dim3((CHWo + 255) / 256, chunkImgs / 64), 256, 0, stream>>>(
          CF, outS + (size_t)c * chunkImgs * CHWo, thin, ss, Co, HW, kzn, osplit);
    }
    k_wxform<<<xgrid, 256, 0, stream>>>(Wa[li], WT, Ci, Co);
    int aosplit = 4 * CHWo;
    k_cmfma<float, false, 4, 1><<<dim3(Co / 64, 4 * atpi, akz), 256, 0, stream>>>(
        inY, WT, Ba[li], y4, Ci, Co, W, aTRI, atpi, 1, 4, nch / akz, (size_t)aosplit);
    k_tty<<<(4 * CHWo + 255) / 256, 256, 0, stream>>>(y4, outY, ys, Co, HW, akz, aosplit);
    k_thr<<<(Co + 255) / 256, 256, 0, stream>>>(thin, ss, ys, out + outoff, Co,
                                                1.0f / (4.f * HW * 64.f));
    ++stage;
  };

  auto pool_stage = [&](const uint8_t* inS, uint8_t* outS, const float* inY, float* outY,
                        int C, int H, const float* pthr, int outoff, float* Sout) {
    const int Ho = H / 2, HWo = Ho * Ho;
    const int CHWo = C * HWo;
    float* ss = sums + stage * 2048; float* ys = ss + 1024;
    k_ifpool<<<dim3((CHWo + 255) / 256, 4), 256, 0, stream>>>(inS, outS, pthr, ss, Sout, C, H);
    k_ttypool<<<(4 * CHWo + 255) / 256, 256, 0, stream>>>(inY, outY, ys, C, H);
    k_thr<<<(C + 255) / 256, 256, 0, stream>>>(pthr, ss, ys, out + outoff, C,
                                               1.0f / (4.f * HWo * 64.f));
    ++stage;
  };

  // L2: spike MT=256: TRI=8,tpi=4 -> grid(2,256,1); analog aTRI=2,atpi=16
  mfma_layer(SA, SB, yA, yB, 1, 128, 128, 32, 8, 4, 1, 64, 1, nullptr,
             2, 16, 1, TH[1], 528);
  // P1
  pool_stage(SB, SA, yB, yA, 128, 32, P[0], 3216, nullptr);
  // L3: spike MT=256 = full img: TRI=16,tpi=1, kz=2 -> grid(4,64,2)
  mfma_layer(SA, SB, yA, yB, 2, 128, 256, 16, 16, 1, 1, 64, 2,
             (float*)(SB + 16777216), 4, 4, 2, TH[2], 656);
  // L4
  mfma_layer(SB, SA, yB, yA, 3, 256, 256, 16, 16, 1, 1, 64, 2,
             (float*)(SA + 16777216), 4, 4, 2, TH[3], 912);
  // P2
  pool_stage(SA, SB, yA, yB, 256, 16, P[1], 3344, nullptr);
  // L5: spike MT=256 = 4 imgs: NIMG=4,TRI=8,tpi=1, kz=2 -> grid(8,32,2)
  mfma_layer(SB, SA, yB, yA, 4, 256, 512, 8, 8, 1, 4, 128, 2,
             (float*)(SA + 8388608), 8, 1, 4, TH[4], 1168);
  // L6
  mfma_layer(SA, SB, yA, yB, 5, 512, 512, 8, 8, 1, 4, 128, 2,
             (float*)(SB + 8388608), 8, 1, 4, TH[5], 1680);
  // P3
  pool_stage(SB, SA, yB, yA, 512, 8, P[2], 3600, nullptr);
  // L7 (pad=0): spike <GW=8,NPG=1> kz=4, partials in SA tail; analog akz=8
  {
    float* ss = sums + stage * 2048; float* ys = ss + 1024;
    float* CF = (float*)(SA + 4194304);         // 4 partials x 4.2 MB
    const size_t osplit = 1048576;              // 256*1024*4 elems
    int xgrid = (16 * 16 * 9 * 4 * 64 + 255) / 256;
    k_wxform<<<xgrid, 256, 0, stream>>>(Ws[6], WT, 512, 1024);
    k_cmfma<uint8_t, true, 8, 1><<<dim3(16, 8, 4), 256, 0, stream>>>(
        SA, WT, Bs[6], CF, 512, 1024, 4, 0, 1, 0, 256, 4, osplit);
    k_if<<<dim3(16, 4), 256, 0, stream>>>(CF, SB, TH[6], ss, 1024, 4, 4, osplit);
    k_wxform<<<xgrid, 256, 0, stream>>>(Wa[6], WT, 512, 1024);
    k_cmfma<float, true, 4, 1><<<dim3(16, 1, 8), 256, 0, stream>>>(
        yA, WT, Ba[6], y4, 512, 1024, 4, 0, 1, 0, 4, 2, 16384);
    k_tty<<<64, 256, 0, stream>>>(y4, yB, ys, 1024, 4, 8, 16384);
    k_thr<<<4, 256, 0, stream>>>(TH[6], ss, ys, out + 2192, 1024, 1.0f / 1024.f);
    ++stage;
  }
  // P4: fused pool+IF also writes S directly
  pool_stage(SB, SA, yB, yA, 1024, 2, P[3], 4112, S);
  // classifier
  k_cls<<<2, 256, 0, stream>>>(S, wc, bc, out);
}